// Round 1
// baseline (3761.506 us; speedup 1.0000x reference)
//
#include <hip/hip_runtime.h>
#include <math.h>

#define NHc 4
#define HDc 32
#define Ec 128
#define Sc 64
#define EPSc 1e-5f
#define BBc 16
#define IN_STRIDE 260

// h[b][s][e] = b_in[e] + sum_d x[b][s][d] * w_in[d][e]
__global__ __launch_bounds__(256) void k_init_h(const float* __restrict__ x,
    const float* __restrict__ w_in, const float* __restrict__ b_in,
    float* __restrict__ h, int total) {
  int idx = blockIdx.x * 256 + threadIdx.x;
  if (idx >= total) return;
  int e = idx & 127;
  int bs = idx >> 7;
  float v = b_in[e] + x[bs*3]*w_in[e] + x[bs*3+1]*w_in[128+e] + x[bs*3+2]*w_in[256+e];
  h[idx] = v;
}

__device__ __forceinline__ float log_sigmoid(float x) {
  return (x >= 0.f) ? -log1pf(expf(-x)) : (x - log1pf(expf(x)));
}

// Fused LN1 + gates einsum + sLSTM scan + multihead-LN + residual.
// One WG = 16 batch rows, loops s = 0..63.
// LDS: Wl[512 rows][64] (row r = (hh*32+k)*4+g; cols 0..31 = wg[g,hh,k,:],
//      cols 32..63 = R[hh,:,g,k]; quad-XOR swizzled) + inb[16][260]
//      (inb[b][hh*64+d] = hn, inb[b][hh*64+32+d] = y).
__global__ __launch_bounds__(256) void k_scan(float* __restrict__ h,
    const float* __restrict__ wg, const float* __restrict__ rk,
    const float* __restrict__ bcell, const float* __restrict__ ln1w,
    const float* __restrict__ gnw) {
  extern __shared__ float lds[];
  float* Wl  = lds;              // 512*64 floats
  float* inb = lds + 512 * 64;   // 16*260 floats
  const int tid = threadIdx.x;
  const int bbase = blockIdx.x * BBc;

  // ---- stage weights (once) ----
  for (int r = tid; r < 512; r += 256) {
    int cqr = r >> 2, g = r & 3;
    int hhr = cqr >> 5, kr = cqr & 31;
    int sw = cqr & 7;
    #pragma unroll
    for (int c = 0; c < 64; c++) {
      float v;
      if (c < 32) v = wg[((g*NHc + hhr)*HDc + kr)*HDc + c];
      else        v = rk[((hhr*HDc + (c-32))*4 + g)*HDc + kr];
      Wl[r*64 + ((((c >> 2) ^ sw) << 2) | (c & 3))] = v;
    }
  }
  for (int i = tid; i < BBc*IN_STRIDE; i += 256) inb[i] = 0.f;

  // phase A/C mapping: 16 lanes per batch row
  const int b_l  = tid >> 4;
  const int hh_a = (tid >> 2) & 3;
  const int sub  = tid & 3;
  const int col0 = hh_a*32 + sub*8;
  float lnw[8], gw[8];
  #pragma unroll
  for (int j = 0; j < 8; j++) { lnw[j] = ln1w[col0+j]; gw[j] = gnw[col0+j]; }

  // phase B mapping: thread owns state channel (hh,kk), all 4 gates, 8 batches
  const int cq = tid >> 1;
  const int bh = tid & 1;
  const int hh = cq >> 5, kk = cq & 31;
  float bias[4];
  #pragma unroll
  for (int g = 0; g < 4; g++) bias[g] = bcell[(g*NHc + hh)*HDc + kk];

  float cs[8], ns[8], ms[8];
  #pragma unroll
  for (int j = 0; j < 8; j++) { cs[j] = 0.f; ns[j] = 0.f; ms[j] = 0.f; }

  __syncthreads();

  for (int s = 0; s < Sc; s++) {
    // ---- Phase A: LN1 over full 128-row (16 lanes/row, shfl-reduce) ----
    float* hrow = h + ((size_t)(bbase + b_l)*Sc + s)*Ec + col0;
    float hv[8];
    *(float4*)&hv[0] = *(const float4*)&hrow[0];
    *(float4*)&hv[4] = *(const float4*)&hrow[4];
    float sum = 0.f, sq = 0.f;
    #pragma unroll
    for (int j = 0; j < 8; j++) { sum += hv[j]; sq += hv[j]*hv[j]; }
    #pragma unroll
    for (int mask = 1; mask < 16; mask <<= 1) {
      sum += __shfl_xor(sum, mask);
      sq  += __shfl_xor(sq,  mask);
    }
    float mu = sum * (1.f/128.f);
    float rs = rsqrtf(sq*(1.f/128.f) - mu*mu + EPSc);
    {
      float hnv[8];
      #pragma unroll
      for (int j = 0; j < 8; j++) hnv[j] = (hv[j]-mu)*rs*lnw[j];
      float* ip = &inb[b_l*IN_STRIDE + hh_a*64 + sub*8];
      *(float4*)&ip[0] = *(float4*)&hnv[0];
      *(float4*)&ip[4] = *(float4*)&hnv[4];
    }
    __syncthreads();

    // ---- Phase B1: raw[g] = bias + hn.wg + y.R  (dot-64 per gate) ----
    float a0[8], a1[8], a2[8], a3[8];
    #pragma unroll
    for (int j = 0; j < 8; j++) { a0[j]=bias[0]; a1[j]=bias[1]; a2[j]=bias[2]; a3[j]=bias[3]; }
    const int sw = cq & 7;
    #pragma unroll 4
    for (int q = 0; q < 16; q++) {
      int k0 = q * 4;
      int qs = ((q ^ sw) << 2);
      float4 w0 = *(float4*)&Wl[(cq*4+0)*64 + qs];
      float4 w1 = *(float4*)&Wl[(cq*4+1)*64 + qs];
      float4 w2 = *(float4*)&Wl[(cq*4+2)*64 + qs];
      float4 w3 = *(float4*)&Wl[(cq*4+3)*64 + qs];
      #pragma unroll
      for (int j = 0; j < 8; j++) {
        float4 iv = *(float4*)&inb[(bh*8+j)*IN_STRIDE + hh*64 + k0];
        a0[j] += iv.x*w0.x + iv.y*w0.y + iv.z*w0.z + iv.w*w0.w;
        a1[j] += iv.x*w1.x + iv.y*w1.y + iv.z*w1.z + iv.w*w1.w;
        a2[j] += iv.x*w2.x + iv.y*w2.y + iv.z*w2.z + iv.w*w2.w;
        a3[j] += iv.x*w3.x + iv.y*w3.y + iv.z*w3.z + iv.w*w3.w;
      }
    }
    // ---- state update (registers) ----
    float yn[8];
    #pragma unroll
    for (int j = 0; j < 8; j++) {
      float iraw = a0[j], fraw = a1[j], zraw = a2[j], oraw = a3[j];
      float lfm  = ms[j] + log_sigmoid(fraw);
      float mnew = (ns[j] == 0.f) ? iraw : fmaxf(iraw, lfm);
      float og = 1.f / (1.f + expf(-oraw));
      float ig = expf(iraw - mnew);
      float fg = expf(lfm  - mnew);
      float cn = fg*cs[j] + ig*tanhf(zraw);
      float nn = fg*ns[j] + ig;
      cs[j] = cn; ns[j] = nn; ms[j] = mnew;
      yn[j] = og * cn / nn;
    }
    __syncthreads();
    // ---- B2: publish new y ----
    #pragma unroll
    for (int j = 0; j < 8; j++)
      inb[(bh*8+j)*IN_STRIDE + hh*64 + 32 + kk] = yn[j];
    __syncthreads();
    // ---- Phase C: mh_ln over HD=32 (4 lanes/(b,head)) + residual ----
    float yv[8];
    {
      float* yp = &inb[b_l*IN_STRIDE + hh_a*64 + 32 + sub*8];
      *(float4*)&yv[0] = *(float4*)&yp[0];
      *(float4*)&yv[4] = *(float4*)&yp[4];
    }
    float s2 = 0.f, q2 = 0.f;
    #pragma unroll
    for (int j = 0; j < 8; j++) { s2 += yv[j]; q2 += yv[j]*yv[j]; }
    s2 += __shfl_xor(s2, 1); q2 += __shfl_xor(q2, 1);
    s2 += __shfl_xor(s2, 2); q2 += __shfl_xor(q2, 2);
    float mu2 = s2 * (1.f/32.f);
    float rs2 = rsqrtf(q2*(1.f/32.f) - mu2*mu2 + EPSc);
    #pragma unroll
    for (int j = 0; j < 8; j++) hv[j] += (yv[j]-mu2)*rs2*gw[j];
    *(float4*)&hrow[0] = *(float4*)&hv[0];
    *(float4*)&hrow[4] = *(float4*)&hv[4];
    // no barrier needed: next A writes hn-slices, disjoint from y-slices read here
  }
}

// Fused LN2 + up-proj + exact GELU*up + down-proj + residual.
// WG = 64 tokens. LDS: hnT[128][64], actT[128][64], wst[128][64] (staged W).
__global__ __launch_bounds__(256) void k_ffn(float* __restrict__ h,
    const float* __restrict__ ln2w, const float* __restrict__ wup,
    const float* __restrict__ wdn) {
  extern __shared__ float lds[];
  float* hnT  = lds;
  float* actT = lds + 8192;
  float* wst  = lds + 16384;
  const int tid = threadIdx.x;
  const size_t tok0 = (size_t)blockIdx.x * 64;

  // ---- LN2 (4 lanes per token) -> hnT transposed ----
  {
    int tok = tid >> 2, sb = tid & 3;
    const float* hrow = h + (tok0 + tok)*Ec + sb*32;
    float v[32];
    #pragma unroll
    for (int q = 0; q < 8; q++) *(float4*)&v[q*4] = *(const float4*)&hrow[q*4];
    float sum = 0.f, sq = 0.f;
    #pragma unroll
    for (int j = 0; j < 32; j++) { sum += v[j]; sq += v[j]*v[j]; }
    sum += __shfl_xor(sum, 1); sq += __shfl_xor(sq, 1);
    sum += __shfl_xor(sum, 2); sq += __shfl_xor(sq, 2);
    float mu = sum * (1.f/128.f);
    float rs = rsqrtf(sq*(1.f/128.f) - mu*mu + EPSc);
    #pragma unroll
    for (int j = 0; j < 32; j++)
      hnT[(sb*32+j)*64 + tok] = (v[j]-mu)*rs*ln2w[sb*32+j];
  }
  __syncthreads();

  const int tq = tid & 15, pq = tid >> 4;
  // ---- up-proj in 4 phases of 32 (gate,upv) pairs ----
  #pragma unroll 1
  for (int ph = 0; ph < 4; ph++) {
    if (ph) __syncthreads();
    #pragma unroll
    for (int i = 0; i < 8; i++) {
      int f = tid*4 + i*1024;
      int kr = f >> 6, c2 = f & 63;
      int col = (c2 < 32) ? (ph*32 + c2) : (96 + ph*32 + c2);
      *(float4*)&wst[kr*64 + c2] = *(const float4*)&wup[kr*256 + col];
    }
    __syncthreads();
    float ag[2][4] = {{0,0,0,0},{0,0,0,0}}, au[2][4] = {{0,0,0,0},{0,0,0,0}};
    #pragma unroll 4
    for (int k = 0; k < 128; k++) {
      float4 hvv4 = *(float4*)&hnT[k*64 + tq*4];
      float2 wgv = *(float2*)&wst[k*64 + pq*2];
      float2 wuv = *(float2*)&wst[k*64 + 32 + pq*2];
      float hvv[4] = {hvv4.x, hvv4.y, hvv4.z, hvv4.w};
      #pragma unroll
      for (int t4 = 0; t4 < 4; t4++) {
        ag[0][t4] += hvv[t4]*wgv.x;
        ag[1][t4] += hvv[t4]*wgv.y;
        au[0][t4] += hvv[t4]*wuv.x;
        au[1][t4] += hvv[t4]*wuv.y;
      }
    }
    #pragma unroll
    for (int p = 0; p < 2; p++) {
      #pragma unroll
      for (int t4 = 0; t4 < 4; t4++) {
        float g = ag[p][t4], u = au[p][t4];
        float a = 0.5f*g*(1.f + erff(g*0.70710678118654752f))*u;  // exact GELU
        actT[(ph*32 + pq*2 + p)*64 + tq*4 + t4] = a;
      }
    }
  }

  // ---- down-proj in 2 phases of 64 e-cols, + residual ----
  const int eq = pq;
  #pragma unroll 1
  for (int eh = 0; eh < 2; eh++) {
    __syncthreads();
    #pragma unroll
    for (int i = 0; i < 8; i++) {
      int f = tid*4 + i*1024;
      int cr = f >> 6, e2 = f & 63;
      *(float4*)&wst[cr*64 + e2] = *(const float4*)&wdn[cr*128 + eh*64 + e2];
    }
    __syncthreads();
    float acc[4][4] = {{0,0,0,0},{0,0,0,0},{0,0,0,0},{0,0,0,0}};
    #pragma unroll 2
    for (int c = 0; c < 128; c++) {
      float4 av4 = *(float4*)&actT[c*64 + tq*4];
      float4 wv4 = *(float4*)&wst[c*64 + eq*4];
      float avv[4] = {av4.x, av4.y, av4.z, av4.w};
      float wvv[4] = {wv4.x, wv4.y, wv4.z, wv4.w};
      #pragma unroll
      for (int t4 = 0; t4 < 4; t4++)
        #pragma unroll
        for (int e4 = 0; e4 < 4; e4++)
          acc[t4][e4] += avv[t4]*wvv[e4];
    }
    #pragma unroll
    for (int t4 = 0; t4 < 4; t4++) {
      float* hp = h + (tok0 + tq*4 + t4)*Ec + eh*64 + eq*4;
      float4 o = *(float4*)hp;
      o.x += acc[t4][0]; o.y += acc[t4][1]; o.z += acc[t4][2]; o.w += acc[t4][3];
      *(float4*)hp = o;
    }
  }
}

// post-LN of h[:, -1] then dot with w_out; one wave per batch row
__global__ __launch_bounds__(256) void k_out(const float* __restrict__ h,
    const float* __restrict__ postw, const float* __restrict__ wout,
    const float* __restrict__ bout, float* __restrict__ out, int B) {
  int gw = (blockIdx.x * blockDim.x + threadIdx.x) >> 6;
  int lane = threadIdx.x & 63;
  if (gw >= B) return;
  const float* row = h + ((size_t)gw*Sc + (Sc-1))*Ec;
  float v0 = row[lane], v1 = row[64+lane];
  float sum = v0+v1, sq = v0*v0+v1*v1;
  #pragma unroll
  for (int m = 1; m < 64; m <<= 1) { sum += __shfl_xor(sum, m); sq += __shfl_xor(sq, m); }
  float mu = sum * (1.f/128.f);
  float rs = rsqrtf(sq*(1.f/128.f) - mu*mu + EPSc);
  float d = (v0-mu)*rs*postw[lane]*wout[lane] + (v1-mu)*rs*postw[64+lane]*wout[64+lane];
  #pragma unroll
  for (int m = 1; m < 64; m <<= 1) d += __shfl_xor(d, m);
  if (lane == 0) out[gw] = d + bout[0];
}

extern "C" void kernel_launch(void* const* d_in, const int* in_sizes, int n_in,
                              void* d_out, int out_size, void* d_ws, size_t ws_size,
                              hipStream_t stream) {
  const float* x     = (const float*)d_in[0];
  const float* w_in  = (const float*)d_in[1];
  const float* b_in  = (const float*)d_in[2];
  const float* ln1_w = (const float*)d_in[3];
  const float* wg    = (const float*)d_in[4];
  const float* rk    = (const float*)d_in[5];
  const float* bcell = (const float*)d_in[6];
  const float* gn_w  = (const float*)d_in[7];
  const float* ln2_w = (const float*)d_in[8];
  const float* wup   = (const float*)d_in[9];
  const float* wdn   = (const float*)d_in[10];
  const float* postw = (const float*)d_in[11];
  const float* w_out = (const float*)d_in[12];
  const float* b_out = (const float*)d_in[13];
  float* out = (float*)d_out;
  float* h   = (float*)d_ws;   // 4096*64*128 fp32 = 134 MB

  const int B = 4096;
  const int total = B * Sc * Ec;

  const int scan_lds = (512*64 + BBc*IN_STRIDE) * 4;  // 147712 B
  const int ffn_lds  = 3 * 8192 * 4;                  // 98304 B
  hipFuncSetAttribute((const void*)k_scan, hipFuncAttributeMaxDynamicSharedMemorySize, scan_lds);
  hipFuncSetAttribute((const void*)k_ffn,  hipFuncAttributeMaxDynamicSharedMemorySize, ffn_lds);

  k_init_h<<<total/256, 256, 0, stream>>>(x, w_in, b_in, h, total);
  for (int ib = 0; ib < 2; ib++) {
    k_scan<<<B/BBc, 256, scan_lds, stream>>>(h,
        wg + ib*16384, rk + ib*16384, bcell + ib*512,
        ln1_w + ib*128, gn_w + ib*128);
    k_ffn<<<(B*Sc)/64, 256, ffn_lds, stream>>>(h,
        ln2_w + ib*128, wup + ib*32768, wdn + ib*16384);
  }
  k_out<<<B/4, 256, 0, stream>>>(h, postw, w_out, b_out, out, B);
}

// Round 4
// 749.523 us; speedup vs baseline: 5.0185x; 5.0185x over previous
//
#include <hip/hip_runtime.h>
#include <math.h>

#define Bc 4096
#define NHc 4
#define HDc 32
#define Ec 128
#define Sc 64
#define EPSc 1e-5f

using bf16x8 = __attribute__((ext_vector_type(8))) short;
using f32x4  = __attribute__((ext_vector_type(4))) float;

#define MFMA(a,b,c) __builtin_amdgcn_mfma_f32_16x16x32_bf16((a),(b),(c),0,0,0)
#define RCP(x) __builtin_amdgcn_rcpf(x)

__device__ __forceinline__ short f2bf(float f) {
  union { float f; unsigned u; } v; v.f = f;
  unsigned r = v.u + 0x7fffu + ((v.u >> 16) & 1u);
  return (short)(r >> 16);
}
__device__ __forceinline__ float bf2f(short s) {
  union { unsigned u; float f; } v; v.u = ((unsigned)(unsigned short)s) << 16;
  return v.f;
}
__device__ __forceinline__ unsigned packsplit(float v) {
  short h16 = f2bf(v);
  short l16 = f2bf(v - bf2f(h16));
  return (unsigned)(unsigned short)h16 | ((unsigned)(unsigned short)l16 << 16);
}
__device__ __forceinline__ void unpack8(uint4 a, uint4 b, bf16x8& Ah, bf16x8& Al) {
  unsigned uu[8] = {a.x, a.y, a.z, a.w, b.x, b.y, b.z, b.w};
  #pragma unroll
  for (int j = 0; j < 8; j++) {
    Ah[j] = (short)(uu[j] & 0xffffu);
    Al[j] = (short)(uu[j] >> 16);
  }
}

// ---------------- h init: h = x @ w_in + b_in ----------------
__global__ __launch_bounds__(256) void k_init_h(const float* __restrict__ x,
    const float* __restrict__ w_in, const float* __restrict__ b_in,
    float* __restrict__ h, int total) {
  int idx = blockIdx.x * 256 + threadIdx.x;
  if (idx >= total) return;
  int e = idx & 127;
  int bs = idx >> 7;
  float v = b_in[e] + x[bs*3]*w_in[e] + x[bs*3+1]*w_in[128+e] + x[bs*3+2]*w_in[256+e];
  h[idx] = v;
}

// ---------------- weight prep: fp32 -> hi/lo bf16 fragment order ----------------
// wch/wcl[ib][hh][nt 0..7][kf 0..1][lane][j]: scan weights (combined wg|R);
//   col n=nt*16+(l&15) -> (g=n>>5,o=n&31); k=kf*32+(l>>4)*8+j;
//   k<32: wg[g][hh][o][k];  k>=32: rk[hh][k-32][g][o]
// wuph/wupl[ib][nt 0..15][kf 0..3][lane][j] = wup[k][n]
// wdnh/wdnl[ib][nt 0..7][kf 0..3][lane][j]  = wdn[k][n]
__global__ void k_prep_w(const float* __restrict__ wg, const float* __restrict__ rk,
    const float* __restrict__ wup, const float* __restrict__ wdn,
    short* __restrict__ wch, short* __restrict__ wcl,
    short* __restrict__ wuph, short* __restrict__ wupl,
    short* __restrict__ wdnh, short* __restrict__ wdnl) {
  int ib = blockIdx.x;
  int tid = threadIdx.x;
  const float* wgp = wg + ib*16384;   // [4][NH][HD(o)][HD(d)]
  const float* rkp = rk + ib*16384;   // [NH][HD(d)][4][HD(o)]
  for (int idx = tid; idx < 32768; idx += 256) {
    int j = idx & 7, lane = (idx>>3)&63, kf = (idx>>9)&1, nt = (idx>>10)&7, hh = idx>>13;
    int n = nt*16 + (lane&15); int g = n>>5, o = n&31;
    int k = kf*32 + (lane>>4)*8 + j;
    float v = (k < 32) ? wgp[((g*NHc+hh)*HDc + o)*HDc + k]
                       : rkp[((hh*HDc + (k-32))*4 + g)*HDc + o];
    short hi16 = f2bf(v);
    wch[ib*32768 + idx] = hi16;
    wcl[ib*32768 + idx] = f2bf(v - bf2f(hi16));
  }
  const float* wupp = wup + ib*32768;  // [128][256]
  for (int idx = tid; idx < 32768; idx += 256) {
    int j = idx&7, lane=(idx>>3)&63, kf=(idx>>9)&3, nt = idx>>11;
    int n = nt*16 + (lane&15); int k = kf*32 + (lane>>4)*8 + j;
    float v = wupp[k*256 + n];
    short hi16 = f2bf(v);
    wuph[ib*32768 + idx] = hi16;
    wupl[ib*32768 + idx] = f2bf(v - bf2f(hi16));
  }
  const float* wdnp = wdn + ib*16384;  // [128][128]
  for (int idx = tid; idx < 16384; idx += 256) {
    int j = idx&7, lane=(idx>>3)&63, kf=(idx>>9)&3, nt = idx>>11;
    int n = nt*16+(lane&15); int k = kf*32+(lane>>4)*8+j;
    float v = wdnp[k*128 + n];
    short hi16 = f2bf(v);
    wdnh[ib*16384 + idx] = hi16;
    wdnl[ib*16384 + idx] = f2bf(v - bf2f(hi16));
  }
}

// ---------------- fused scan: LN1 + gates(split-bf16 MFMA) + cell + mh_ln + resid ----
// WG = 16 batches, 4 waves (one per head). 1 WG/CU.
__global__ __launch_bounds__(256, 1) void k_scan3(float* __restrict__ h,
    const short* __restrict__ wch, const short* __restrict__ wcl,
    const float* __restrict__ bcell, const float* __restrict__ ln1w,
    const float* __restrict__ gnw) {
  __shared__ short ybh[4][16][32];     // raw-y hi, per head: [batch][chan]
  __shared__ short ybl[4][16][32];     // raw-y lo
  __shared__ float ynorm[4][16][32];   // normalized y for residual
  __shared__ float LNp[2][4][16][2];   // LN partials, double-buffered
  const int tid = threadIdx.x;
  const int hh = tid >> 6, lane = tid & 63;
  const int l15 = lane & 15, hi = lane >> 4;
  const int bg = blockIdx.x;

  // B fragments hi/lo (128 VGPRs)
  bf16x8 Bh[8][2], Bl[8][2];
  #pragma unroll
  for (int nt = 0; nt < 8; nt++)
    #pragma unroll
    for (int kf = 0; kf < 2; kf++) {
      int off = ((hh*16 + nt*2+kf)*64 + lane)*8;
      Bh[nt][kf] = *(const bf16x8*)(wch + off);
      Bl[nt][kf] = *(const bf16x8*)(wcl + off);
    }

  float biasv[8];
  #pragma unroll
  for (int nt = 0; nt < 8; nt++) {
    int n = nt*16 + l15;
    biasv[nt] = bcell[((n>>5)*NHc + hh)*HDc + (n&31)];
  }
  float lnw[8];
  #pragma unroll
  for (int j = 0; j < 8; j++) lnw[j] = ln1w[hh*32 + hi*8 + j];
  const float gwv0 = gnw[hh*32 + l15];
  const float gwv1 = gnw[hh*32 + 16 + l15];

  for (int i = lane; i < 512; i += 64) { ybh[hh][i>>5][i&31] = 0; ybl[hh][i>>5][i&31] = 0; }

  float cs[4][2], ns[4][2], ms[4][2];
  #pragma unroll
  for (int r = 0; r < 4; r++)
    #pragma unroll
    for (int q = 0; q < 2; q++) { cs[r][q]=0.f; ns[r][q]=0.f; ms[r][q]=0.f; }

  const float* hbase = h + ((size_t)(bg*16 + l15)*Sc)*Ec + hh*32 + hi*8;
  float4 ha = *(const float4*)(hbase);
  float4 hb = *(const float4*)(hbase + 4);

  for (int s = 0; s < Sc; s++) {
    float hv[8];
    *(float4*)&hv[0] = ha; *(float4*)&hv[4] = hb;
    if (s < 63) {  // prefetch next step's h row-slice
      ha = *(const float4*)(hbase + (s+1)*Ec);
      hb = *(const float4*)(hbase + (s+1)*Ec + 4);
    }
    // LN1 partials: 8 cols per lane; combine across hi-groups (same row l15)
    float sum = 0.f, sq = 0.f;
    #pragma unroll
    for (int j = 0; j < 8; j++) { sum += hv[j]; sq += hv[j]*hv[j]; }
    sum += __shfl_xor(sum, 16); sq += __shfl_xor(sq, 16);
    sum += __shfl_xor(sum, 32); sq += __shfl_xor(sq, 32);
    if (hi == 0) { LNp[s&1][hh][l15][0] = sum; LNp[s&1][hh][l15][1] = sq; }
    __syncthreads();
    float tsum = LNp[s&1][0][l15][0] + LNp[s&1][1][l15][0]
               + LNp[s&1][2][l15][0] + LNp[s&1][3][l15][0];
    float tsq  = LNp[s&1][0][l15][1] + LNp[s&1][1][l15][1]
               + LNp[s&1][2][l15][1] + LNp[s&1][3][l15][1];
    float mu = tsum * (1.f/128.f);
    float rs = rsqrtf(tsq*(1.f/128.f) - mu*mu + EPSc);

    // hn A-frag hi/lo (lane = row l15, k = hi*8+j)
    bf16x8 Ah, Al;
    #pragma unroll
    for (int j = 0; j < 8; j++) {
      float hn = (hv[j]-mu)*rs*lnw[j];
      short h16 = f2bf(hn);
      Ah[j] = h16;
      Al[j] = f2bf(hn - bf2f(h16));
    }
    bf16x8 Yh = *(const bf16x8*)&ybh[hh][l15][hi*8];
    bf16x8 Yl = *(const bf16x8*)&ybl[hh][l15][hi*8];

    f32x4 acc[8];
    #pragma unroll
    for (int nt = 0; nt < 8; nt++) {
      f32x4 c; c[0]=biasv[nt]; c[1]=biasv[nt]; c[2]=biasv[nt]; c[3]=biasv[nt];
      c = MFMA(Ah, Bh[nt][0], c);
      c = MFMA(Ah, Bl[nt][0], c);
      c = MFMA(Al, Bh[nt][0], c);
      c = MFMA(Yh, Bh[nt][1], c);
      c = MFMA(Yh, Bl[nt][1], c);
      acc[nt] = MFMA(Yl, Bh[nt][1], c);
    }

    // cell update: lane owns chans o=q*16+l15, batches hi*4+r
    float yv[4][2], sumr[4], sqr[4];
    #pragma unroll
    for (int r = 0; r < 4; r++) {
      sumr[r] = 0.f; sqr[r] = 0.f;
      #pragma unroll
      for (int q = 0; q < 2; q++) {
        float iraw = acc[0+q][r];
        float fraw = acc[2+q][r];
        float zraw = acc[4+q][r];
        float oraw = acc[6+q][r];
        float ax  = fabsf(fraw);
        float lsg = fminf(fraw, 0.f) - __logf(1.f + __expf(-ax));
        float lfm = ms[r][q] + lsg;
        float mnew = (ns[r][q] == 0.f) ? iraw : fmaxf(iraw, lfm);
        float og = RCP(1.f + __expf(-oraw));
        float ig = __expf(iraw - mnew);
        float fg = __expf(lfm - mnew);
        float e2 = __expf(2.f*zraw);
        float th = 1.f - 2.f*RCP(e2 + 1.f);
        float cn = fg*cs[r][q] + ig*th;
        float nn = fg*ns[r][q] + ig;
        cs[r][q] = cn; ns[r][q] = nn; ms[r][q] = mnew;
        float y = og*cn*RCP(nn);
        yv[r][q] = y;
        sumr[r] += y; sqr[r] += y*y;
        short y16 = f2bf(y);
        ybh[hh][hi*4+r][q*16+l15] = y16;
        ybl[hh][hi*4+r][q*16+l15] = f2bf(y - bf2f(y16));
      }
    }
    // mh_ln (over 32 chans: 16 l15-lanes x 2 q) -> ynorm
    #pragma unroll
    for (int r = 0; r < 4; r++) {
      float sm = sumr[r], qq = sqr[r];
      sm += __shfl_xor(sm,1); qq += __shfl_xor(qq,1);
      sm += __shfl_xor(sm,2); qq += __shfl_xor(qq,2);
      sm += __shfl_xor(sm,4); qq += __shfl_xor(qq,4);
      sm += __shfl_xor(sm,8); qq += __shfl_xor(qq,8);
      float mu2 = sm * (1.f/32.f);
      float rs2 = rsqrtf(qq*(1.f/32.f) - mu2*mu2 + EPSc);
      ynorm[hh][hi*4+r][l15]    = (yv[r][0]-mu2)*rs2*gwv0;
      ynorm[hh][hi*4+r][16+l15] = (yv[r][1]-mu2)*rs2*gwv1;
    }
    // residual into register-held h rows (read back in A-layout), store
    float4 y0 = *(const float4*)&ynorm[hh][l15][hi*8];
    float4 y1 = *(const float4*)&ynorm[hh][l15][hi*8+4];
    float4 o0, o1;
    o0.x = hv[0]+y0.x; o0.y = hv[1]+y0.y; o0.z = hv[2]+y0.z; o0.w = hv[3]+y0.w;
    o1.x = hv[4]+y1.x; o1.y = hv[5]+y1.y; o1.z = hv[6]+y1.z; o1.w = hv[7]+y1.w;
    *(float4*)(hbase + (size_t)s*Ec)     = o0;
    *(float4*)(hbase + (size_t)s*Ec + 4) = o1;
  }
}

// ---------------- fused FFN (fp32-grade): LN2 + up + GELU*up + down + residual ----
// One LDS buffer [64 tok][128] of packed (hi|lo) bf16 pairs, reused hn -> act.
__global__ __launch_bounds__(256) void k_ffn3(float* __restrict__ h,
    const float* __restrict__ ln2w,
    const short* __restrict__ wuph, const short* __restrict__ wupl,
    const short* __restrict__ wdnh, const short* __restrict__ wdnl) {
  __shared__ unsigned buf[8192];   // 32 KB, XOR-swizzled (^((row&7)<<4) on byte addr)
  size_t tok0 = (size_t)blockIdx.x * 64;
  int tid = threadIdx.x;
  int wv = tid >> 6, lane = tid & 63, l15 = lane & 15, hi = lane >> 4;

  { // LN2 -> buf (packed split)
    int t = tid >> 2, sub = tid & 3;
    const float* row = h + (tok0 + t)*Ec + sub*32;
    float v[32];
    #pragma unroll
    for (int q = 0; q < 8; q++) *(float4*)&v[q*4] = *(const float4*)&row[q*4];
    float sum = 0.f, sq = 0.f;
    #pragma unroll
    for (int j = 0; j < 32; j++) { sum += v[j]; sq += v[j]*v[j]; }
    sum += __shfl_xor(sum,1); sq += __shfl_xor(sq,1);
    sum += __shfl_xor(sum,2); sq += __shfl_xor(sq,2);
    float mu = sum * (1.f/128.f);
    float rs = rsqrtf(sq*(1.f/128.f) - mu*mu + EPSc);
    #pragma unroll
    for (int q2 = 0; q2 < 8; q2++) {
      uint4 pk;
      pk.x = packsplit((v[q2*4+0]-mu)*rs*ln2w[sub*32+q2*4+0]);
      pk.y = packsplit((v[q2*4+1]-mu)*rs*ln2w[sub*32+q2*4+1]);
      pk.z = packsplit((v[q2*4+2]-mu)*rs*ln2w[sub*32+q2*4+2]);
      pk.w = packsplit((v[q2*4+3]-mu)*rs*ln2w[sub*32+q2*4+3]);
      int byte = (t*512 + sub*128 + q2*16) ^ ((t&7)<<4);
      *(uint4*)((char*)buf + byte) = pk;
    }
  }
  __syncthreads();

  // up GEMM: wave wv -> gate ntiles {2wv,2wv+1}, up ntiles {8+2wv,8+2wv+1}
  f32x4 ag[2][4], au[2][4];
  #pragma unroll
  for (int p = 0; p < 2; p++)
    #pragma unroll
    for (int mt = 0; mt < 4; mt++)
      #pragma unroll
      for (int r = 0; r < 4; r++) { ag[p][mt][r]=0.f; au[p][mt][r]=0.f; }
  #pragma unroll 1
  for (int kf = 0; kf < 4; kf++) {
    bf16x8 Ah[4], Al[4];
    #pragma unroll
    for (int mt = 0; mt < 4; mt++) {
      int rw = mt*16 + l15;
      int b0 = rw*512 + kf*128 + hi*32, sw = (rw&7)<<4;
      uint4 u0 = *(const uint4*)((const char*)buf + ((b0)    ^ sw));
      uint4 u1 = *(const uint4*)((const char*)buf + ((b0+16) ^ sw));
      unpack8(u0, u1, Ah[mt], Al[mt]);
    }
    #pragma unroll
    for (int p = 0; p < 2; p++) {
      int gOff = (((2*wv+p)*4 + kf)*64 + lane)*8;
      int uOff = (((8+2*wv+p)*4 + kf)*64 + lane)*8;
      bf16x8 Bgh = *(const bf16x8*)(wuph + gOff);
      bf16x8 Bgl = *(const bf16x8*)(wupl + gOff);
      bf16x8 Buh = *(const bf16x8*)(wuph + uOff);
      bf16x8 Bul = *(const bf16x8*)(wupl + uOff);
      #pragma unroll
      for (int mt = 0; mt < 4; mt++) {
        ag[p][mt] = MFMA(Ah[mt], Bgh, ag[p][mt]);
        ag[p][mt] = MFMA(Ah[mt], Bgl, ag[p][mt]);
        ag[p][mt] = MFMA(Al[mt], Bgh, ag[p][mt]);
        au[p][mt] = MFMA(Ah[mt], Buh, au[p][mt]);
        au[p][mt] = MFMA(Ah[mt], Bul, au[p][mt]);
        au[p][mt] = MFMA(Al[mt], Buh, au[p][mt]);
      }
    }
  }
  __syncthreads();
  // exact GELU(gate)*up -> buf (packed split)
  #pragma unroll
  for (int p = 0; p < 2; p++)
    #pragma unroll
    for (int mt = 0; mt < 4; mt++)
      #pragma unroll
      for (int r = 0; r < 4; r++) {
        float g = ag[p][mt][r], u = au[p][mt][r];
        float a = 0.5f*g*(1.f + erff(g*0.70710678118654752f))*u;
        int m = mt*16 + hi*4 + r, f = (2*wv+p)*16 + l15;
        int byte = (m*512 + f*4) ^ ((m&7)<<4);
        *(unsigned*)((char*)buf + byte) = packsplit(a);
      }
  __syncthreads();

  // down GEMM: wave wv -> e ntiles {2wv,2wv+1}; + residual
  f32x4 oc[2][4];
  #pragma unroll
  for (int p = 0; p < 2; p++)
    #pragma unroll
    for (int mt = 0; mt < 4; mt++)
      #pragma unroll
      for (int r = 0; r < 4; r++) oc[p][mt][r] = 0.f;
  #pragma unroll 1
  for (int kf = 0; kf < 4; kf++) {
    bf16x8 Ah[4], Al[4];
    #pragma unroll
    for (int mt = 0; mt < 4; mt++) {
      int rw = mt*16 + l15;
      int b0 = rw*512 + kf*128 + hi*32, sw = (rw&7)<<4;
      uint4 u0 = *(const uint4*)((const char*)buf + ((b0)    ^ sw));
      uint4 u1 = *(const uint4*)((const char*)buf + ((b0+16) ^ sw));
      unpack8(u0, u1, Ah[mt], Al[mt]);
    }
    #pragma unroll
    for (int p = 0; p < 2; p++) {
      int dOff = (((2*wv+p)*4 + kf)*64 + lane)*8;
      bf16x8 Bdh = *(const bf16x8*)(wdnh + dOff);
      bf16x8 Bdl = *(const bf16x8*)(wdnl + dOff);
      #pragma unroll
      for (int mt = 0; mt < 4; mt++) {
        oc[p][mt] = MFMA(Ah[mt], Bdh, oc[p][mt]);
        oc[p][mt] = MFMA(Ah[mt], Bdl, oc[p][mt]);
        oc[p][mt] = MFMA(Al[mt], Bdh, oc[p][mt]);
      }
    }
  }
  #pragma unroll
  for (int p = 0; p < 2; p++)
    #pragma unroll
    for (int mt = 0; mt < 4; mt++)
      #pragma unroll
      for (int r = 0; r < 4; r++) {
        int m = mt*16 + hi*4 + r, e = (2*wv+p)*16 + l15;
        float* hp = h + (tok0 + m)*Ec + e;
        *hp += oc[p][mt][r];
      }
}

// ---------------- output head ----------------
__global__ __launch_bounds__(256) void k_out(const float* __restrict__ h,
    const float* __restrict__ postw, const float* __restrict__ wout,
    const float* __restrict__ bout, float* __restrict__ out, int B) {
  int gw = (blockIdx.x * blockDim.x + threadIdx.x) >> 6;
  int lane = threadIdx.x & 63;
  if (gw >= B) return;
  const float* row = h + ((size_t)gw*Sc + (Sc-1))*Ec;
  float v0 = row[lane], v1 = row[64+lane];
  float sum = v0+v1, sq = v0*v0+v1*v1;
  #pragma unroll
  for (int m = 1; m < 64; m <<= 1) { sum += __shfl_xor(sum, m); sq += __shfl_xor(sq, m); }
  float mu = sum * (1.f/128.f);
  float rs = rsqrtf(sq*(1.f/128.f) - mu*mu + EPSc);
  float d = (v0-mu)*rs*postw[lane]*wout[lane] + (v1-mu)*rs*postw[64+lane]*wout[64+lane];
  #pragma unroll
  for (int m = 1; m < 64; m <<= 1) d += __shfl_xor(d, m);
  if (lane == 0) out[gw] = d + bout[0];
}

extern "C" void kernel_launch(void* const* d_in, const int* in_sizes, int n_in,
                              void* d_out, int out_size, void* d_ws, size_t ws_size,
                              hipStream_t stream) {
  const float* x     = (const float*)d_in[0];
  const float* w_in  = (const float*)d_in[1];
  const float* b_in  = (const float*)d_in[2];
  const float* ln1_w = (const float*)d_in[3];
  const float* wg    = (const float*)d_in[4];
  const float* rk    = (const float*)d_in[5];
  const float* bcell = (const float*)d_in[6];
  const float* gn_w  = (const float*)d_in[7];
  const float* ln2_w = (const float*)d_in[8];
  const float* wup   = (const float*)d_in[9];
  const float* wdn   = (const float*)d_in[10];
  const float* postw = (const float*)d_in[11];
  const float* w_out = (const float*)d_in[12];
  const float* b_out = (const float*)d_in[13];
  float* out = (float*)d_out;

  char* p = (char*)d_ws;
  float* h    = (float*)p;            p += 134217728;   // [4096][64][128] fp32
  short* wch  = (short*)p;            p += 131072;
  short* wcl  = (short*)p;            p += 131072;
  short* wuph = (short*)p;            p += 131072;
  short* wupl = (short*)p;            p += 131072;
  short* wdnh = (short*)p;            p += 65536;
  short* wdnl = (short*)p;            p += 65536;

  k_prep_w<<<2, 256, 0, stream>>>(wg, rk, wup, wdn, wch, wcl,
                                  wuph, wupl, wdnh, wdnl);
  k_init_h<<<(Bc*Sc*Ec)/256, 256, 0, stream>>>(x, w_in, b_in, h, Bc*Sc*Ec);
  for (int ib = 0; ib < 2; ib++) {
    k_scan3<<<Bc/16, 256, 0, stream>>>(h, wch + ib*32768, wcl + ib*32768,
                                       bcell + ib*512, ln1_w + ib*128, gn_w + ib*128);
    k_ffn3<<<(Bc*Sc)/64, 256, 0, stream>>>(h, ln2_w + ib*128,
                                           wuph + ib*32768, wupl + ib*32768,
                                           wdnh + ib*16384, wdnl + ib*16384);
  }
  k_out<<<Bc/4, 256, 0, stream>>>(h, postw, w_out, b_out, out, Bc);
}

// Round 5
// 675.164 us; speedup vs baseline: 5.5712x; 1.1101x over previous
//
#include <hip/hip_runtime.h>
#include <math.h>

#define Bc 4096
#define NHc 4
#define HDc 32
#define Ec 128
#define Sc 64
#define EPSc 1e-5f

using bf16x8 = __attribute__((ext_vector_type(8))) short;
using f32x4  = __attribute__((ext_vector_type(4))) float;

#define MFMA(a,b,c) __builtin_amdgcn_mfma_f32_16x16x32_bf16((a),(b),(c),0,0,0)
#define RCP(x) __builtin_amdgcn_rcpf(x)

__device__ __forceinline__ short f2bf(float f) {
  union { float f; unsigned u; } v; v.f = f;
  unsigned r = v.u + 0x7fffu + ((v.u >> 16) & 1u);
  return (short)(r >> 16);
}
__device__ __forceinline__ float bf2f(short s) {
  union { unsigned u; float f; } v; v.u = ((unsigned)(unsigned short)s) << 16;
  return v.f;
}
__device__ __forceinline__ unsigned packsplit(float v) {
  short h16 = f2bf(v);
  short l16 = f2bf(v - bf2f(h16));
  return (unsigned)(unsigned short)h16 | ((unsigned)(unsigned short)l16 << 16);
}
__device__ __forceinline__ void unpack8(uint4 a, uint4 b, bf16x8& Ah, bf16x8& Al) {
  unsigned uu[8] = {a.x, a.y, a.z, a.w, b.x, b.y, b.z, b.w};
  #pragma unroll
  for (int j = 0; j < 8; j++) {
    Ah[j] = (short)(uu[j] & 0xffffu);
    Al[j] = (short)(uu[j] >> 16);
  }
}

// ---------------- h init: h = x @ w_in + b_in ----------------
__global__ __launch_bounds__(256) void k_init_h(const float* __restrict__ x,
    const float* __restrict__ w_in, const float* __restrict__ b_in,
    float* __restrict__ h, int total) {
  int idx = blockIdx.x * 256 + threadIdx.x;
  if (idx >= total) return;
  int e = idx & 127;
  int bs = idx >> 7;
  float v = b_in[e] + x[bs*3]*w_in[e] + x[bs*3+1]*w_in[128+e] + x[bs*3+2]*w_in[256+e];
  h[idx] = v;
}

// ---------------- weight prep: fp32 -> hi/lo bf16 fragment order ----------------
// wch/wcl[ib][hh][nt 0..7][kf 0..1][lane][j]: scan weights (combined wg|R);
//   col n=nt*16+(l&15) -> (g=n>>5,o=n&31); k=kf*32+(l>>4)*8+j;
//   k<32: wg[g][hh][o][k];  k>=32: rk[hh][k-32][g][o]
// wuph/wupl[ib][nt 0..15][kf 0..3][lane][j] = wup[k][n]
// wdnh/wdnl[ib][nt 0..7][kf 0..3][lane][j]  = wdn[k][n]
__global__ void k_prep_w(const float* __restrict__ wg, const float* __restrict__ rk,
    const float* __restrict__ wup, const float* __restrict__ wdn,
    short* __restrict__ wch, short* __restrict__ wcl,
    short* __restrict__ wuph, short* __restrict__ wupl,
    short* __restrict__ wdnh, short* __restrict__ wdnl) {
  int ib = blockIdx.x;
  int tid = threadIdx.x;
  const float* wgp = wg + ib*16384;   // [4][NH][HD(o)][HD(d)]
  const float* rkp = rk + ib*16384;   // [NH][HD(d)][4][HD(o)]
  for (int idx = tid; idx < 32768; idx += 256) {
    int j = idx & 7, lane = (idx>>3)&63, kf = (idx>>9)&1, nt = (idx>>10)&7, hh = idx>>13;
    int n = nt*16 + (lane&15); int g = n>>5, o = n&31;
    int k = kf*32 + (lane>>4)*8 + j;
    float v = (k < 32) ? wgp[((g*NHc+hh)*HDc + o)*HDc + k]
                       : rkp[((hh*HDc + (k-32))*4 + g)*HDc + o];
    short hi16 = f2bf(v);
    wch[ib*32768 + idx] = hi16;
    wcl[ib*32768 + idx] = f2bf(v - bf2f(hi16));
  }
  const float* wupp = wup + ib*32768;  // [128][256]
  for (int idx = tid; idx < 32768; idx += 256) {
    int j = idx&7, lane=(idx>>3)&63, kf=(idx>>9)&3, nt = idx>>11;
    int n = nt*16 + (lane&15); int k = kf*32 + (lane>>4)*8 + j;
    float v = wupp[k*256 + n];
    short hi16 = f2bf(v);
    wuph[ib*32768 + idx] = hi16;
    wupl[ib*32768 + idx] = f2bf(v - bf2f(hi16));
  }
  const float* wdnp = wdn + ib*16384;  // [128][128]
  for (int idx = tid; idx < 16384; idx += 256) {
    int j = idx&7, lane=(idx>>3)&63, kf=(idx>>9)&3, nt = idx>>11;
    int n = nt*16+(lane&15); int k = kf*32+(lane>>4)*8+j;
    float v = wdnp[k*128 + n];
    short hi16 = f2bf(v);
    wdnh[ib*16384 + idx] = hi16;
    wdnl[ib*16384 + idx] = f2bf(v - bf2f(hi16));
  }
}

// ---------------- fused scan, 8-wave: LN1 + gates(split MFMA) + cell + mh_ln + resid ----
// WG = 16 batches, 8 waves = (head hh, q-half p). 1 WG/CU, 2 waves/SIMD.
// One barrier per step; y double-buffered in LDS; mh_ln+residual deferred one step
// and computed by p==0 from the same Y-fragment the MFMA reads.
__global__ __launch_bounds__(512, 2) void k_scan4(float* __restrict__ h,
    const short* __restrict__ wch, const short* __restrict__ wcl,
    const float* __restrict__ bcell, const float* __restrict__ ln1w,
    const float* __restrict__ gnw) {
  __shared__ short ybh[2][4][16][40];   // [dbuf][head][batch][chan padded to 40]
  __shared__ short ybl[2][4][16][40];
  __shared__ float LNp[2][4][16][2];    // [dbuf][head][batch l15][sum,sq]
  const int tid = threadIdx.x;
  const int wid = tid >> 6;
  const int hh = wid >> 1;        // head
  const int p  = wid & 1;         // q-half (chans p*16..p*16+15)
  const int lane = tid & 63;
  const int l15 = lane & 15, hi = lane >> 4;
  const int bg = blockIdx.x;

  // B fragments for nt = 2*i+p (gate i, q=p), kf = {hn, y}, hi/lo split
  bf16x8 Bh[4][2], Bl[4][2];
  #pragma unroll
  for (int i = 0; i < 4; i++)
    #pragma unroll
    for (int kf = 0; kf < 2; kf++) {
      int off = ((hh*16 + (2*i+p)*2 + kf)*64 + lane)*8;
      Bh[i][kf] = *(const bf16x8*)(wch + off);
      Bl[i][kf] = *(const bf16x8*)(wcl + off);
    }

  float biasv[4];
  #pragma unroll
  for (int i = 0; i < 4; i++)
    biasv[i] = bcell[(i*NHc + hh)*HDc + p*16 + l15];
  float lnw[8], gwv[8];
  #pragma unroll
  for (int j = 0; j < 8; j++) {
    lnw[j] = ln1w[hh*32 + hi*8 + j];
    gwv[j] = gnw[hh*32 + hi*8 + j];
  }

  // zero-init y dbuf[1] (read at s=0)
  for (int i = tid; i < 4*16*40; i += 512) {
    ybh[1][0][0][i] = 0; ybl[1][0][0][i] = 0;
  }

  float cs[4], ns[4], ms[4];
  #pragma unroll
  for (int r = 0; r < 4; r++) { cs[r]=0.f; ns[r]=0.f; ms[r]=0.f; }

  float* hbase = h + ((size_t)(bg*16 + l15)*Sc)*Ec + hh*32 + hi*8;
  float4 ha = *(const float4*)(hbase);
  float4 hb = *(const float4*)(hbase + 4);
  float hvprev[8];

  __syncthreads();

  for (int s = 0; s < Sc; s++) {
    float hv[8];
    *(float4*)&hv[0] = ha; *(float4*)&hv[4] = hb;
    if (s < 63) {  // prefetch next step's h row-slice (in flight across the step)
      ha = *(const float4*)(hbase + (s+1)*Ec);
      hb = *(const float4*)(hbase + (s+1)*Ec + 4);
    }
    // ---- LN1 partials (per head; p==0 publishes) ----
    float sum = 0.f, sq = 0.f;
    #pragma unroll
    for (int j = 0; j < 8; j++) { sum += hv[j]; sq += hv[j]*hv[j]; }
    sum += __shfl_xor(sum, 16); sq += __shfl_xor(sq, 16);
    sum += __shfl_xor(sum, 32); sq += __shfl_xor(sq, 32);
    if (p == 0 && hi == 0) { LNp[s&1][hh][l15][0] = sum; LNp[s&1][hh][l15][1] = sq; }
    __syncthreads();
    float tsum = LNp[s&1][0][l15][0] + LNp[s&1][1][l15][0]
               + LNp[s&1][2][l15][0] + LNp[s&1][3][l15][0];
    float tsq  = LNp[s&1][0][l15][1] + LNp[s&1][1][l15][1]
               + LNp[s&1][2][l15][1] + LNp[s&1][3][l15][1];
    float mu = tsum * (1.f/128.f);
    float rs = rsqrtf(tsq*(1.f/128.f) - mu*mu + EPSc);

    // ---- hn A-frag hi/lo (row = batch l15, k = hi*8+j) ----
    bf16x8 Ah, Al;
    #pragma unroll
    for (int j = 0; j < 8; j++) {
      float hn = (hv[j]-mu)*rs*lnw[j];
      short h16 = f2bf(hn);
      Ah[j] = h16;
      Al[j] = f2bf(hn - bf2f(h16));
    }
    // ---- Y frag of step s-1 (row = batch l15, k = chan hi*8+j) ----
    const int sbY = (s&1)^1;
    bf16x8 Yh = *(const bf16x8*)&ybh[sbY][hh][l15][hi*8];
    bf16x8 Yl = *(const bf16x8*)&ybl[sbY][hh][l15][hi*8];

    // ---- deferred mh_ln + residual for step s-1 (p==0 wave only) ----
    if (s && p == 0) {
      float y8[8], s2 = 0.f, q2 = 0.f;
      #pragma unroll
      for (int j = 0; j < 8; j++) {
        y8[j] = bf2f(Yh[j]) + bf2f(Yl[j]);
        s2 += y8[j]; q2 += y8[j]*y8[j];
      }
      s2 += __shfl_xor(s2, 16); q2 += __shfl_xor(q2, 16);
      s2 += __shfl_xor(s2, 32); q2 += __shfl_xor(q2, 32);
      float mu2 = s2 * (1.f/32.f);
      float rs2 = rsqrtf(q2*(1.f/32.f) - mu2*mu2 + EPSc);
      float4 o0, o1;
      o0.x = hvprev[0] + (y8[0]-mu2)*rs2*gwv[0];
      o0.y = hvprev[1] + (y8[1]-mu2)*rs2*gwv[1];
      o0.z = hvprev[2] + (y8[2]-mu2)*rs2*gwv[2];
      o0.w = hvprev[3] + (y8[3]-mu2)*rs2*gwv[3];
      o1.x = hvprev[4] + (y8[4]-mu2)*rs2*gwv[4];
      o1.y = hvprev[5] + (y8[5]-mu2)*rs2*gwv[5];
      o1.z = hvprev[6] + (y8[6]-mu2)*rs2*gwv[6];
      o1.w = hvprev[7] + (y8[7]-mu2)*rs2*gwv[7];
      *(float4*)(hbase + (size_t)(s-1)*Ec)     = o0;
      *(float4*)(hbase + (size_t)(s-1)*Ec + 4) = o1;
    }
    #pragma unroll
    for (int j = 0; j < 8; j++) hvprev[j] = hv[j];

    // ---- gates MFMA: 4 ntiles (gate i, q=p) x 6 split terms ----
    f32x4 acc[4];
    #pragma unroll
    for (int i = 0; i < 4; i++) {
      f32x4 c; c[0]=biasv[i]; c[1]=biasv[i]; c[2]=biasv[i]; c[3]=biasv[i];
      c = MFMA(Ah, Bh[i][0], c);
      c = MFMA(Ah, Bl[i][0], c);
      c = MFMA(Al, Bh[i][0], c);
      c = MFMA(Yh, Bh[i][1], c);
      c = MFMA(Yh, Bl[i][1], c);
      acc[i] = MFMA(Yl, Bh[i][1], c);
    }

    // ---- cell update: lane owns chan o=p*16+l15, batches hi*4+r ----
    #pragma unroll
    for (int r = 0; r < 4; r++) {
      float iraw = acc[0][r];
      float fraw = acc[1][r];
      float zraw = acc[2][r];
      float oraw = acc[3][r];
      float ax  = fabsf(fraw);
      float lsg = fminf(fraw, 0.f) - __logf(1.f + __expf(-ax));
      float lfm = ms[r] + lsg;
      float mnew = (ns[r] == 0.f) ? iraw : fmaxf(iraw, lfm);
      float og = RCP(1.f + __expf(-oraw));
      float ig = __expf(iraw - mnew);
      float fg = __expf(lfm - mnew);
      float e2 = __expf(2.f*zraw);
      float th = 1.f - 2.f*RCP(e2 + 1.f);
      float cn = fg*cs[r] + ig*th;
      float nn = fg*ns[r] + ig;
      cs[r] = cn; ns[r] = nn; ms[r] = mnew;
      float y = og*cn*RCP(nn);
      short y16 = f2bf(y);
      ybh[s&1][hh][hi*4+r][p*16+l15] = y16;
      ybl[s&1][hh][hi*4+r][p*16+l15] = f2bf(y - bf2f(y16));
    }
  }

  // ---- epilogue: mh_ln + residual for s=63 ----
  __syncthreads();
  if (p == 0) {
    bf16x8 Yh = *(const bf16x8*)&ybh[(Sc-1)&1][hh][l15][hi*8];
    bf16x8 Yl = *(const bf16x8*)&ybl[(Sc-1)&1][hh][l15][hi*8];
    float y8[8], s2 = 0.f, q2 = 0.f;
    #pragma unroll
    for (int j = 0; j < 8; j++) {
      y8[j] = bf2f(Yh[j]) + bf2f(Yl[j]);
      s2 += y8[j]; q2 += y8[j]*y8[j];
    }
    s2 += __shfl_xor(s2, 16); q2 += __shfl_xor(q2, 16);
    s2 += __shfl_xor(s2, 32); q2 += __shfl_xor(q2, 32);
    float mu2 = s2 * (1.f/32.f);
    float rs2 = rsqrtf(q2*(1.f/32.f) - mu2*mu2 + EPSc);
    float4 o0, o1;
    o0.x = hvprev[0] + (y8[0]-mu2)*rs2*gwv[0];
    o0.y = hvprev[1] + (y8[1]-mu2)*rs2*gwv[1];
    o0.z = hvprev[2] + (y8[2]-mu2)*rs2*gwv[2];
    o0.w = hvprev[3] + (y8[3]-mu2)*rs2*gwv[3];
    o1.x = hvprev[4] + (y8[4]-mu2)*rs2*gwv[4];
    o1.y = hvprev[5] + (y8[5]-mu2)*rs2*gwv[5];
    o1.z = hvprev[6] + (y8[6]-mu2)*rs2*gwv[6];
    o1.w = hvprev[7] + (y8[7]-mu2)*rs2*gwv[7];
    *(float4*)(hbase + (size_t)(Sc-1)*Ec)     = o0;
    *(float4*)(hbase + (size_t)(Sc-1)*Ec + 4) = o1;
  }
}

// ---------------- fused FFN (fp32-grade): LN2 + up + GELU*up + down + residual ----
// One LDS buffer [64 tok][128] of packed (hi|lo) bf16 pairs, reused hn -> act.
__global__ __launch_bounds__(256) void k_ffn3(float* __restrict__ h,
    const float* __restrict__ ln2w,
    const short* __restrict__ wuph, const short* __restrict__ wupl,
    const short* __restrict__ wdnh, const short* __restrict__ wdnl) {
  __shared__ unsigned buf[8192];   // 32 KB, XOR-swizzled (^((row&7)<<4) on byte addr)
  size_t tok0 = (size_t)blockIdx.x * 64;
  int tid = threadIdx.x;
  int wv = tid >> 6, lane = tid & 63, l15 = lane & 15, hi = lane >> 4;

  { // LN2 -> buf (packed split)
    int t = tid >> 2, sub = tid & 3;
    const float* row = h + (tok0 + t)*Ec + sub*32;
    float v[32];
    #pragma unroll
    for (int q = 0; q < 8; q++) *(float4*)&v[q*4] = *(const float4*)&row[q*4];
    float sum = 0.f, sq = 0.f;
    #pragma unroll
    for (int j = 0; j < 32; j++) { sum += v[j]; sq += v[j]*v[j]; }
    sum += __shfl_xor(sum,1); sq += __shfl_xor(sq,1);
    sum += __shfl_xor(sum,2); sq += __shfl_xor(sq,2);
    float mu = sum * (1.f/128.f);
    float rs = rsqrtf(sq*(1.f/128.f) - mu*mu + EPSc);
    #pragma unroll
    for (int q2 = 0; q2 < 8; q2++) {
      uint4 pk;
      pk.x = packsplit((v[q2*4+0]-mu)*rs*ln2w[sub*32+q2*4+0]);
      pk.y = packsplit((v[q2*4+1]-mu)*rs*ln2w[sub*32+q2*4+1]);
      pk.z = packsplit((v[q2*4+2]-mu)*rs*ln2w[sub*32+q2*4+2]);
      pk.w = packsplit((v[q2*4+3]-mu)*rs*ln2w[sub*32+q2*4+3]);
      int byte = (t*512 + sub*128 + q2*16) ^ ((t&7)<<4);
      *(uint4*)((char*)buf + byte) = pk;
    }
  }
  __syncthreads();

  // up GEMM: wave wv -> gate ntiles {2wv,2wv+1}, up ntiles {8+2wv,8+2wv+1}
  f32x4 ag[2][4], au[2][4];
  #pragma unroll
  for (int p = 0; p < 2; p++)
    #pragma unroll
    for (int mt = 0; mt < 4; mt++)
      #pragma unroll
      for (int r = 0; r < 4; r++) { ag[p][mt][r]=0.f; au[p][mt][r]=0.f; }
  #pragma unroll 1
  for (int kf = 0; kf < 4; kf++) {
    bf16x8 Ah[4], Al[4];
    #pragma unroll
    for (int mt = 0; mt < 4; mt++) {
      int rw = mt*16 + l15;
      int b0 = rw*512 + kf*128 + hi*32, sw = (rw&7)<<4;
      uint4 u0 = *(const uint4*)((const char*)buf + ((b0)    ^ sw));
      uint4 u1 = *(const uint4*)((const char*)buf + ((b0+16) ^ sw));
      unpack8(u0, u1, Ah[mt], Al[mt]);
    }
    #pragma unroll
    for (int p = 0; p < 2; p++) {
      int gOff = (((2*wv+p)*4 + kf)*64 + lane)*8;
      int uOff = (((8+2*wv+p)*4 + kf)*64 + lane)*8;
      bf16x8 Bgh = *(const bf16x8*)(wuph + gOff);
      bf16x8 Bgl = *(const bf16x8*)(wupl + gOff);
      bf16x8 Buh = *(const bf16x8*)(wuph + uOff);
      bf16x8 Bul = *(const bf16x8*)(wupl + uOff);
      #pragma unroll
      for (int mt = 0; mt < 4; mt++) {
        ag[p][mt] = MFMA(Ah[mt], Bgh, ag[p][mt]);
        ag[p][mt] = MFMA(Ah[mt], Bgl, ag[p][mt]);
        ag[p][mt] = MFMA(Al[mt], Bgh, ag[p][mt]);
        au[p][mt] = MFMA(Ah[mt], Buh, au[p][mt]);
        au[p][mt] = MFMA(Ah[mt], Bul, au[p][mt]);
        au[p][mt] = MFMA(Al[mt], Buh, au[p][mt]);
      }
    }
  }
  __syncthreads();
  // exact GELU(gate)*up -> buf (packed split)
  #pragma unroll
  for (int p = 0; p < 2; p++)
    #pragma unroll
    for (int mt = 0; mt < 4; mt++)
      #pragma unroll
      for (int r = 0; r < 4; r++) {
        float g = ag[p][mt][r], u = au[p][mt][r];
        float a = 0.5f*g*(1.f + erff(g*0.70710678118654752f))*u;
        int m = mt*16 + hi*4 + r, f = (2*wv+p)*16 + l15;
        int byte = (m*512 + f*4) ^ ((m&7)<<4);
        *(unsigned*)((char*)buf + byte) = packsplit(a);
      }
  __syncthreads();

  // down GEMM: wave wv -> e ntiles {2wv,2wv+1}; + residual
  f32x4 oc[2][4];
  #pragma unroll
  for (int p = 0; p < 2; p++)
    #pragma unroll
    for (int mt = 0; mt < 4; mt++)
      #pragma unroll
      for (int r = 0; r < 4; r++) oc[p][mt][r] = 0.f;
  #pragma unroll 1
  for (int kf = 0; kf < 4; kf++) {
    bf16x8 Ah[4], Al[4];
    #pragma unroll
    for (int mt = 0; mt < 4; mt++) {
      int rw = mt*16 + l15;
      int b0 = rw*512 + kf*128 + hi*32, sw = (rw&7)<<4;
      uint4 u0 = *(const uint4*)((const char*)buf + ((b0)    ^ sw));
      uint4 u1 = *(const uint4*)((const char*)buf + ((b0+16) ^ sw));
      unpack8(u0, u1, Ah[mt], Al[mt]);
    }
    #pragma unroll
    for (int p = 0; p < 2; p++) {
      int dOff = (((2*wv+p)*4 + kf)*64 + lane)*8;
      bf16x8 Bdh = *(const bf16x8*)(wdnh + dOff);
      bf16x8 Bdl = *(const bf16x8*)(wdnl + dOff);
      #pragma unroll
      for (int mt = 0; mt < 4; mt++) {
        oc[p][mt] = MFMA(Ah[mt], Bdh, oc[p][mt]);
        oc[p][mt] = MFMA(Ah[mt], Bdl, oc[p][mt]);
        oc[p][mt] = MFMA(Al[mt], Bdh, oc[p][mt]);
      }
    }
  }
  #pragma unroll
  for (int p = 0; p < 2; p++)
    #pragma unroll
    for (int mt = 0; mt < 4; mt++)
      #pragma unroll
      for (int r = 0; r < 4; r++) {
        int m = mt*16 + hi*4 + r, e = (2*wv+p)*16 + l15;
        float* hp = h + (tok0 + m)*Ec + e;
        *hp += oc[p][mt][r];
      }
}

// ---------------- output head ----------------
__global__ __launch_bounds__(256) void k_out(const float* __restrict__ h,
    const float* __restrict__ postw, const float* __restrict__ wout,
    const float* __restrict__ bout, float* __restrict__ out, int B) {
  int gw = (blockIdx.x * blockDim.x + threadIdx.x) >> 6;
  int lane = threadIdx.x & 63;
  if (gw >= B) return;
  const float* row = h + ((size_t)gw*Sc + (Sc-1))*Ec;
  float v0 = row[lane], v1 = row[64+lane];
  float sum = v0+v1, sq = v0*v0+v1*v1;
  #pragma unroll
  for (int m = 1; m < 64; m <<= 1) { sum += __shfl_xor(sum, m); sq += __shfl_xor(sq, m); }
  float mu = sum * (1.f/128.f);
  float rs = rsqrtf(sq*(1.f/128.f) - mu*mu + EPSc);
  float d = (v0-mu)*rs*postw[lane]*wout[lane] + (v1-mu)*rs*postw[64+lane]*wout[64+lane];
  #pragma unroll
  for (int m = 1; m < 64; m <<= 1) d += __shfl_xor(d, m);
  if (lane == 0) out[gw] = d + bout[0];
}

extern "C" void kernel_launch(void* const* d_in, const int* in_sizes, int n_in,
                              void* d_out, int out_size, void* d_ws, size_t ws_size,
                              hipStream_t stream) {
  const float* x     = (const float*)d_in[0];
  const float* w_in  = (const float*)d_in[1];
  const float* b_in  = (const float*)d_in[2];
  const float* ln1_w = (const float*)d_in[3];
  const float* wg    = (const float*)d_in[4];
  const float* rk    = (const float*)d_in[5];
  const float* bcell = (const float*)d_in[6];
  const float* gn_w  = (const float*)d_in[7];
  const float* ln2_w = (const float*)d_in[8];
  const float* wup   = (const float*)d_in[9];
  const float* wdn   = (const float*)d_in[10];
  const float* postw = (const float*)d_in[11];
  const float* w_out = (const float*)d_in[12];
  const float* b_out = (const float*)d_in[13];
  float* out = (float*)d_out;

  char* p = (char*)d_ws;
  float* h    = (float*)p;            p += 134217728;   // [4096][64][128] fp32
  short* wch  = (short*)p;            p += 131072;
  short* wcl  = (short*)p;            p += 131072;
  short* wuph = (short*)p;            p += 131072;
  short* wupl = (short*)p;            p += 131072;
  short* wdnh = (short*)p;            p += 65536;
  short* wdnl = (short*)p;            p += 65536;

  k_prep_w<<<2, 256, 0, stream>>>(wg, rk, wup, wdn, wch, wcl,
                                  wuph, wupl, wdnh, wdnl);
  k_init_h<<<(Bc*Sc*Ec)/256, 256, 0, stream>>>(x, w_in, b_in, h, Bc*Sc*Ec);
  for (int ib = 0; ib < 2; ib++) {
    k_scan4<<<Bc/16, 512, 0, stream>>>(h, wch + ib*32768, wcl + ib*32768,
                                       bcell + ib*512, ln1_w + ib*128, gn_w + ib*128);
    k_ffn3<<<(Bc*Sc)/64, 256, 0, stream>>>(h, ln2_w + ib*128,
                                           wuph + ib*32768, wupl + ib*32768,
                                           wdnh + ib*16384, wdnl + ib*16384);
  }
  k_out<<<Bc/4, 256, 0, stream>>>(h, postw, w_out, b_out, out, Bc);
}

// Round 6
// 615.217 us; speedup vs baseline: 6.1141x; 1.0974x over previous
//
#include <hip/hip_runtime.h>
#include <math.h>

#define Bc 4096
#define NHc 4
#define HDc 32
#define Ec 128
#define Sc 64
#define EPSc 1e-5f

using bf16x8 = __attribute__((ext_vector_type(8))) short;
using f32x4  = __attribute__((ext_vector_type(4))) float;

#define MFMA(a,b,c) __builtin_amdgcn_mfma_f32_16x16x32_bf16((a),(b),(c),0,0,0)
#define RCP(x) __builtin_amdgcn_rcpf(x)

__device__ __forceinline__ short f2bf(float f) {
  union { float f; unsigned u; } v; v.f = f;
  unsigned r = v.u + 0x7fffu + ((v.u >> 16) & 1u);
  return (short)(r >> 16);
}
__device__ __forceinline__ float bf2f(short s) {
  union { unsigned u; float f; } v; v.u = ((unsigned)(unsigned short)s) << 16;
  return v.f;
}

// exact-grade GELU via A&S 7.1.26 erf poly (|err| <= 1.5e-7, ~14 VALU ops)
__device__ __forceinline__ float gelu_exact(float g) {
  float x  = g * 0.70710678118654752f;
  float ax = fabsf(x);
  float t  = RCP(1.f + 0.3275911f*ax);
  float y  = t*(0.254829592f + t*(-0.284496736f + t*(1.421413741f
           + t*(-1.453152027f + t*1.061405429f))));
  float e  = __expf(-ax*ax);
  float er = 1.f - y*e;             // erf(|x|)
  er = (x < 0.f) ? -er : er;
  return 0.5f*g*(1.f + er);
}

// ---------------- h init: h = x @ w_in + b_in ----------------
__global__ __launch_bounds__(256) void k_init_h(const float* __restrict__ x,
    const float* __restrict__ w_in, const float* __restrict__ b_in,
    float* __restrict__ h, int total) {
  int idx = blockIdx.x * 256 + threadIdx.x;
  if (idx >= total) return;
  int e = idx & 127;
  int bs = idx >> 7;
  float v = b_in[e] + x[bs*3]*w_in[e] + x[bs*3+1]*w_in[128+e] + x[bs*3+2]*w_in[256+e];
  h[idx] = v;
}

// ---------------- weight prep: fp32 -> hi/lo bf16 fragment order ----------------
// wch/wcl[ib][hh][nt 0..7][kf 0..1][lane][j]: scan weights (combined wg|R);
//   col n=nt*16+(l&15) -> (g=n>>5,o=n&31); k=kf*32+(l>>4)*8+j;
//   k<32: wg[g][hh][o][k];  k>=32: rk[hh][k-32][g][o]
// wuph/wupl[ib][nt 0..15][kf 0..3][lane][j] = wup[k][n]
// wdnh/wdnl[ib][nt 0..7][kf 0..3][lane][j]  = wdn[k][n]
__global__ void k_prep_w(const float* __restrict__ wg, const float* __restrict__ rk,
    const float* __restrict__ wup, const float* __restrict__ wdn,
    short* __restrict__ wch, short* __restrict__ wcl,
    short* __restrict__ wuph, short* __restrict__ wupl,
    short* __restrict__ wdnh, short* __restrict__ wdnl) {
  int ib = blockIdx.x;
  int tid = threadIdx.x;
  const float* wgp = wg + ib*16384;   // [4][NH][HD(o)][HD(d)]
  const float* rkp = rk + ib*16384;   // [NH][HD(d)][4][HD(o)]
  for (int idx = tid; idx < 32768; idx += 256) {
    int j = idx & 7, lane = (idx>>3)&63, kf = (idx>>9)&1, nt = (idx>>10)&7, hh = idx>>13;
    int n = nt*16 + (lane&15); int g = n>>5, o = n&31;
    int k = kf*32 + (lane>>4)*8 + j;
    float v = (k < 32) ? wgp[((g*NHc+hh)*HDc + o)*HDc + k]
                       : rkp[((hh*HDc + (k-32))*4 + g)*HDc + o];
    short hi16 = f2bf(v);
    wch[ib*32768 + idx] = hi16;
    wcl[ib*32768 + idx] = f2bf(v - bf2f(hi16));
  }
  const float* wupp = wup + ib*32768;  // [128][256]
  for (int idx = tid; idx < 32768; idx += 256) {
    int j = idx&7, lane=(idx>>3)&63, kf=(idx>>9)&3, nt = idx>>11;
    int n = nt*16 + (lane&15); int k = kf*32 + (lane>>4)*8 + j;
    float v = wupp[k*256 + n];
    short hi16 = f2bf(v);
    wuph[ib*32768 + idx] = hi16;
    wupl[ib*32768 + idx] = f2bf(v - bf2f(hi16));
  }
  const float* wdnp = wdn + ib*16384;  // [128][128]
  for (int idx = tid; idx < 16384; idx += 256) {
    int j = idx&7, lane=(idx>>3)&63, kf=(idx>>9)&3, nt = idx>>11;
    int n = nt*16+(lane&15); int k = kf*32+(lane>>4)*8+j;
    float v = wdnp[k*128 + n];
    short hi16 = f2bf(v);
    wdnh[ib*16384 + idx] = hi16;
    wdnl[ib*16384 + idx] = f2bf(v - bf2f(hi16));
  }
}

// ---------------- fused scan, 8-wave: LN1 + gates(split MFMA) + cell + mh_ln + resid ----
// WG = 16 batches, 8 waves = (head hh, q-half p). 1 WG/CU, 2 waves/SIMD.
__global__ __launch_bounds__(512, 2) void k_scan4(float* __restrict__ h,
    const short* __restrict__ wch, const short* __restrict__ wcl,
    const float* __restrict__ bcell, const float* __restrict__ ln1w,
    const float* __restrict__ gnw) {
  __shared__ short ybh[2][4][16][40];   // [dbuf][head][batch][chan padded to 40]
  __shared__ short ybl[2][4][16][40];
  __shared__ float LNp[2][4][16][2];    // [dbuf][head][batch l15][sum,sq]
  const int tid = threadIdx.x;
  const int wid = tid >> 6;
  const int hh = wid >> 1;        // head
  const int p  = wid & 1;         // q-half (chans p*16..p*16+15)
  const int lane = tid & 63;
  const int l15 = lane & 15, hi = lane >> 4;
  const int bg = blockIdx.x;

  // B fragments for nt = 2*i+p (gate i, q=p), kf = {hn, y}, hi/lo split
  bf16x8 Bh[4][2], Bl[4][2];
  #pragma unroll
  for (int i = 0; i < 4; i++)
    #pragma unroll
    for (int kf = 0; kf < 2; kf++) {
      int off = ((hh*16 + (2*i+p)*2 + kf)*64 + lane)*8;
      Bh[i][kf] = *(const bf16x8*)(wch + off);
      Bl[i][kf] = *(const bf16x8*)(wcl + off);
    }

  float biasv[4];
  #pragma unroll
  for (int i = 0; i < 4; i++)
    biasv[i] = bcell[(i*NHc + hh)*HDc + p*16 + l15];
  float lnw[8], gwv[8];
  #pragma unroll
  for (int j = 0; j < 8; j++) {
    lnw[j] = ln1w[hh*32 + hi*8 + j];
    gwv[j] = gnw[hh*32 + hi*8 + j];
  }

  // zero-init y dbuf[1] (read at s=0)
  for (int i = tid; i < 4*16*40; i += 512) {
    ybh[1][0][0][i] = 0; ybl[1][0][0][i] = 0;
  }

  float cs[4], ns[4], ms[4];
  #pragma unroll
  for (int r = 0; r < 4; r++) { cs[r]=0.f; ns[r]=0.f; ms[r]=0.f; }

  float* hbase = h + ((size_t)(bg*16 + l15)*Sc)*Ec + hh*32 + hi*8;
  float4 ha = *(const float4*)(hbase);
  float4 hb = *(const float4*)(hbase + 4);
  float hvprev[8];

  __syncthreads();

  for (int s = 0; s < Sc; s++) {
    float hv[8];
    *(float4*)&hv[0] = ha; *(float4*)&hv[4] = hb;
    if (s < 63) {  // prefetch next step's h row-slice (in flight across the step)
      ha = *(const float4*)(hbase + (s+1)*Ec);
      hb = *(const float4*)(hbase + (s+1)*Ec + 4);
    }
    // ---- LN1 partials (per head; p==0 publishes) ----
    float sum = 0.f, sq = 0.f;
    #pragma unroll
    for (int j = 0; j < 8; j++) { sum += hv[j]; sq += hv[j]*hv[j]; }
    sum += __shfl_xor(sum, 16); sq += __shfl_xor(sq, 16);
    sum += __shfl_xor(sum, 32); sq += __shfl_xor(sq, 32);
    if (p == 0 && hi == 0) { LNp[s&1][hh][l15][0] = sum; LNp[s&1][hh][l15][1] = sq; }
    __syncthreads();
    float tsum = LNp[s&1][0][l15][0] + LNp[s&1][1][l15][0]
               + LNp[s&1][2][l15][0] + LNp[s&1][3][l15][0];
    float tsq  = LNp[s&1][0][l15][1] + LNp[s&1][1][l15][1]
               + LNp[s&1][2][l15][1] + LNp[s&1][3][l15][1];
    float mu = tsum * (1.f/128.f);
    float rs = rsqrtf(tsq*(1.f/128.f) - mu*mu + EPSc);

    // ---- hn A-frag hi/lo (row = batch l15, k = hi*8+j) ----
    bf16x8 Ah, Al;
    #pragma unroll
    for (int j = 0; j < 8; j++) {
      float hn = (hv[j]-mu)*rs*lnw[j];
      short h16 = f2bf(hn);
      Ah[j] = h16;
      Al[j] = f2bf(hn - bf2f(h16));
    }
    // ---- Y frag of step s-1 (row = batch l15, k = chan hi*8+j) ----
    const int sbY = (s&1)^1;
    bf16x8 Yh = *(const bf16x8*)&ybh[sbY][hh][l15][hi*8];
    bf16x8 Yl = *(const bf16x8*)&ybl[sbY][hh][l15][hi*8];

    // ---- deferred mh_ln + residual for step s-1 (p==0 wave only) ----
    if (s && p == 0) {
      float y8[8], s2 = 0.f, q2 = 0.f;
      #pragma unroll
      for (int j = 0; j < 8; j++) {
        y8[j] = bf2f(Yh[j]) + bf2f(Yl[j]);
        s2 += y8[j]; q2 += y8[j]*y8[j];
      }
      s2 += __shfl_xor(s2, 16); q2 += __shfl_xor(q2, 16);
      s2 += __shfl_xor(s2, 32); q2 += __shfl_xor(q2, 32);
      float mu2 = s2 * (1.f/32.f);
      float rs2 = rsqrtf(q2*(1.f/32.f) - mu2*mu2 + EPSc);
      float4 o0, o1;
      o0.x = hvprev[0] + (y8[0]-mu2)*rs2*gwv[0];
      o0.y = hvprev[1] + (y8[1]-mu2)*rs2*gwv[1];
      o0.z = hvprev[2] + (y8[2]-mu2)*rs2*gwv[2];
      o0.w = hvprev[3] + (y8[3]-mu2)*rs2*gwv[3];
      o1.x = hvprev[4] + (y8[4]-mu2)*rs2*gwv[4];
      o1.y = hvprev[5] + (y8[5]-mu2)*rs2*gwv[5];
      o1.z = hvprev[6] + (y8[6]-mu2)*rs2*gwv[6];
      o1.w = hvprev[7] + (y8[7]-mu2)*rs2*gwv[7];
      *(float4*)(hbase + (size_t)(s-1)*Ec)     = o0;
      *(float4*)(hbase + (size_t)(s-1)*Ec + 4) = o1;
    }
    #pragma unroll
    for (int j = 0; j < 8; j++) hvprev[j] = hv[j];

    // ---- gates MFMA: 4 ntiles (gate i, q=p) x 6 split terms ----
    f32x4 acc[4];
    #pragma unroll
    for (int i = 0; i < 4; i++) {
      f32x4 c; c[0]=biasv[i]; c[1]=biasv[i]; c[2]=biasv[i]; c[3]=biasv[i];
      c = MFMA(Ah, Bh[i][0], c);
      c = MFMA(Ah, Bl[i][0], c);
      c = MFMA(Al, Bh[i][0], c);
      c = MFMA(Yh, Bh[i][1], c);
      c = MFMA(Yh, Bl[i][1], c);
      acc[i] = MFMA(Yl, Bh[i][1], c);
    }

    // ---- cell update: lane owns chan o=p*16+l15, batches hi*4+r ----
    #pragma unroll
    for (int r = 0; r < 4; r++) {
      float iraw = acc[0][r];
      float fraw = acc[1][r];
      float zraw = acc[2][r];
      float oraw = acc[3][r];
      float ax  = fabsf(fraw);
      float lsg = fminf(fraw, 0.f) - __logf(1.f + __expf(-ax));
      float lfm = ms[r] + lsg;
      float mnew = (ns[r] == 0.f) ? iraw : fmaxf(iraw, lfm);
      float og = RCP(1.f + __expf(-oraw));
      float ig = __expf(iraw - mnew);
      float fg = __expf(lfm - mnew);
      float e2 = __expf(2.f*zraw);
      float th = 1.f - 2.f*RCP(e2 + 1.f);
      float cn = fg*cs[r] + ig*th;
      float nn = fg*ns[r] + ig;
      cs[r] = cn; ns[r] = nn; ms[r] = mnew;
      float y = og*cn*RCP(nn);
      short y16 = f2bf(y);
      ybh[s&1][hh][hi*4+r][p*16+l15] = y16;
      ybl[s&1][hh][hi*4+r][p*16+l15] = f2bf(y - bf2f(y16));
    }
  }

  // ---- epilogue: mh_ln + residual for s=63 ----
  __syncthreads();
  if (p == 0) {
    bf16x8 Yh = *(const bf16x8*)&ybh[(Sc-1)&1][hh][l15][hi*8];
    bf16x8 Yl = *(const bf16x8*)&ybl[(Sc-1)&1][hh][l15][hi*8];
    float y8[8], s2 = 0.f, q2 = 0.f;
    #pragma unroll
    for (int j = 0; j < 8; j++) {
      y8[j] = bf2f(Yh[j]) + bf2f(Yl[j]);
      s2 += y8[j]; q2 += y8[j]*y8[j];
    }
    s2 += __shfl_xor(s2, 16); q2 += __shfl_xor(q2, 16);
    s2 += __shfl_xor(s2, 32); q2 += __shfl_xor(q2, 32);
    float mu2 = s2 * (1.f/32.f);
    float rs2 = rsqrtf(q2*(1.f/32.f) - mu2*mu2 + EPSc);
    float4 o0, o1;
    o0.x = hvprev[0] + (y8[0]-mu2)*rs2*gwv[0];
    o0.y = hvprev[1] + (y8[1]-mu2)*rs2*gwv[1];
    o0.z = hvprev[2] + (y8[2]-mu2)*rs2*gwv[2];
    o0.w = hvprev[3] + (y8[3]-mu2)*rs2*gwv[3];
    o1.x = hvprev[4] + (y8[4]-mu2)*rs2*gwv[4];
    o1.y = hvprev[5] + (y8[5]-mu2)*rs2*gwv[5];
    o1.z = hvprev[6] + (y8[6]-mu2)*rs2*gwv[6];
    o1.w = hvprev[7] + (y8[7]-mu2)*rs2*gwv[7];
    *(float4*)(hbase + (size_t)(Sc-1)*Ec)     = o0;
    *(float4*)(hbase + (size_t)(Sc-1)*Ec + 4) = o1;
  }
}

// ---------------- fused FFN (fp32-grade): LN2 + up + GELU*up + down + residual ----
// Separate hi/lo LDS buffers: A-frag reads are direct b128 bf16x8 loads (no unpack).
__global__ __launch_bounds__(256) void k_ffn4(float* __restrict__ h,
    const float* __restrict__ ln2w,
    const short* __restrict__ wuph, const short* __restrict__ wupl,
    const short* __restrict__ wdnh, const short* __restrict__ wdnl) {
  __shared__ short bufH[8192];   // [64 tok][128] hi, XOR-swizzled ^((row&7)<<4)
  __shared__ short bufL[8192];   // [64 tok][128] lo, same layout
  size_t tok0 = (size_t)blockIdx.x * 64;
  int tid = threadIdx.x;
  int wv = tid >> 6, lane = tid & 63, l15 = lane & 15, hi = lane >> 4;

  { // LN2 -> bufH/bufL
    int t = tid >> 2, sub = tid & 3;
    const float* row = h + (tok0 + t)*Ec + sub*32;
    float v[32];
    #pragma unroll
    for (int q = 0; q < 8; q++) *(float4*)&v[q*4] = *(const float4*)&row[q*4];
    float sum = 0.f, sq = 0.f;
    #pragma unroll
    for (int j = 0; j < 32; j++) { sum += v[j]; sq += v[j]*v[j]; }
    sum += __shfl_xor(sum,1); sq += __shfl_xor(sq,1);
    sum += __shfl_xor(sum,2); sq += __shfl_xor(sq,2);
    float mu = sum * (1.f/128.f);
    float rs = rsqrtf(sq*(1.f/128.f) - mu*mu + EPSc);
    #pragma unroll
    for (int q2 = 0; q2 < 4; q2++) {
      bf16x8 ph, pl;
      #pragma unroll
      for (int j = 0; j < 8; j++) {
        float hn = (v[q2*8+j]-mu)*rs*ln2w[sub*32+q2*8+j];
        short h16 = f2bf(hn);
        ph[j] = h16;
        pl[j] = f2bf(hn - bf2f(h16));
      }
      int byte = (t*256 + sub*64 + q2*16) ^ ((t&7)<<4);
      *(bf16x8*)((char*)bufH + byte) = ph;
      *(bf16x8*)((char*)bufL + byte) = pl;
    }
  }
  __syncthreads();

  // up GEMM: wave wv -> gate ntiles {2wv,2wv+1}, up ntiles {8+2wv,8+2wv+1}
  f32x4 ag[2][4], au[2][4];
  #pragma unroll
  for (int p = 0; p < 2; p++)
    #pragma unroll
    for (int mt = 0; mt < 4; mt++)
      #pragma unroll
      for (int r = 0; r < 4; r++) { ag[p][mt][r]=0.f; au[p][mt][r]=0.f; }
  #pragma unroll 1
  for (int kf = 0; kf < 4; kf++) {
    bf16x8 Ah[4], Al[4];
    #pragma unroll
    for (int mt = 0; mt < 4; mt++) {
      int rw = mt*16 + l15;
      int byte = (rw*256 + kf*64 + hi*16) ^ ((rw&7)<<4);
      Ah[mt] = *(const bf16x8*)((const char*)bufH + byte);
      Al[mt] = *(const bf16x8*)((const char*)bufL + byte);
    }
    #pragma unroll
    for (int p = 0; p < 2; p++) {
      int gOff = (((2*wv+p)*4 + kf)*64 + lane)*8;
      int uOff = (((8+2*wv+p)*4 + kf)*64 + lane)*8;
      bf16x8 Bgh = *(const bf16x8*)(wuph + gOff);
      bf16x8 Bgl = *(const bf16x8*)(wupl + gOff);
      bf16x8 Buh = *(const bf16x8*)(wuph + uOff);
      bf16x8 Bul = *(const bf16x8*)(wupl + uOff);
      #pragma unroll
      for (int mt = 0; mt < 4; mt++) {
        ag[p][mt] = MFMA(Ah[mt], Bgh, ag[p][mt]);
        ag[p][mt] = MFMA(Ah[mt], Bgl, ag[p][mt]);
        ag[p][mt] = MFMA(Al[mt], Bgh, ag[p][mt]);
        au[p][mt] = MFMA(Ah[mt], Buh, au[p][mt]);
        au[p][mt] = MFMA(Ah[mt], Bul, au[p][mt]);
        au[p][mt] = MFMA(Al[mt], Buh, au[p][mt]);
      }
    }
  }
  __syncthreads();
  // exact GELU(gate)*up -> bufH/bufL
  #pragma unroll
  for (int p = 0; p < 2; p++)
    #pragma unroll
    for (int mt = 0; mt < 4; mt++)
      #pragma unroll
      for (int r = 0; r < 4; r++) {
        float g = ag[p][mt][r], u = au[p][mt][r];
        float a = gelu_exact(g)*u;
        int m = mt*16 + hi*4 + r, f = (2*wv+p)*16 + l15;
        int byte = (m*256 + f*2) ^ ((m&7)<<4);
        short a16 = f2bf(a);
        *(short*)((char*)bufH + byte) = a16;
        *(short*)((char*)bufL + byte) = f2bf(a - bf2f(a16));
      }
  __syncthreads();

  // down GEMM: wave wv -> e ntiles {2wv,2wv+1}; + residual
  f32x4 oc[2][4];
  #pragma unroll
  for (int p = 0; p < 2; p++)
    #pragma unroll
    for (int mt = 0; mt < 4; mt++)
      #pragma unroll
      for (int r = 0; r < 4; r++) oc[p][mt][r] = 0.f;
  #pragma unroll 1
  for (int kf = 0; kf < 4; kf++) {
    bf16x8 Ah[4], Al[4];
    #pragma unroll
    for (int mt = 0; mt < 4; mt++) {
      int rw = mt*16 + l15;
      int byte = (rw*256 + kf*64 + hi*16) ^ ((rw&7)<<4);
      Ah[mt] = *(const bf16x8*)((const char*)bufH + byte);
      Al[mt] = *(const bf16x8*)((const char*)bufL + byte);
    }
    #pragma unroll
    for (int p = 0; p < 2; p++) {
      int dOff = (((2*wv+p)*4 + kf)*64 + lane)*8;
      bf16x8 Bdh = *(const bf16x8*)(wdnh + dOff);
      bf16x8 Bdl = *(const bf16x8*)(wdnl + dOff);
      #pragma unroll
      for (int mt = 0; mt < 4; mt++) {
        oc[p][mt] = MFMA(Ah[mt], Bdh, oc[p][mt]);
        oc[p][mt] = MFMA(Ah[mt], Bdl, oc[p][mt]);
        oc[p][mt] = MFMA(Al[mt], Bdh, oc[p][mt]);
      }
    }
  }
  #pragma unroll
  for (int p = 0; p < 2; p++)
    #pragma unroll
    for (int mt = 0; mt < 4; mt++)
      #pragma unroll
      for (int r = 0; r < 4; r++) {
        int m = mt*16 + hi*4 + r, e = (2*wv+p)*16 + l15;
        float* hp = h + (tok0 + m)*Ec + e;
        *hp += oc[p][mt][r];
      }
}

// ---------------- output head ----------------
__global__ __launch_bounds__(256) void k_out(const float* __restrict__ h,
    const float* __restrict__ postw, const float* __restrict__ wout,
    const float* __restrict__ bout, float* __restrict__ out, int B) {
  int gw = (blockIdx.x * blockDim.x + threadIdx.x) >> 6;
  int lane = threadIdx.x & 63;
  if (gw >= B) return;
  const float* row = h + ((size_t)gw*Sc + (Sc-1))*Ec;
  float v0 = row[lane], v1 = row[64+lane];
  float sum = v0+v1, sq = v0*v0+v1*v1;
  #pragma unroll
  for (int m = 1; m < 64; m <<= 1) { sum += __shfl_xor(sum, m); sq += __shfl_xor(sq, m); }
  float mu = sum * (1.f/128.f);
  float rs = rsqrtf(sq*(1.f/128.f) - mu*mu + EPSc);
  float d = (v0-mu)*rs*postw[lane]*wout[lane] + (v1-mu)*rs*postw[64+lane]*wout[64+lane];
  #pragma unroll
  for (int m = 1; m < 64; m <<= 1) d += __shfl_xor(d, m);
  if (lane == 0) out[gw] = d + bout[0];
}

extern "C" void kernel_launch(void* const* d_in, const int* in_sizes, int n_in,
                              void* d_out, int out_size, void* d_ws, size_t ws_size,
                              hipStream_t stream) {
  const float* x     = (const float*)d_in[0];
  const float* w_in  = (const float*)d_in[1];
  const float* b_in  = (const float*)d_in[2];
  const float* ln1_w = (const float*)d_in[3];
  const float* wg    = (const float*)d_in[4];
  const float* rk    = (const float*)d_in[5];
  const float* bcell = (const float*)d_in[6];
  const float* gn_w  = (const float*)d_in[7];
  const float* ln2_w = (const float*)d_in[8];
  const float* wup   = (const float*)d_in[9];
  const float* wdn   = (const float*)d_in[10];
  const float* postw = (const float*)d_in[11];
  const float* w_out = (const float*)d_in[12];
  const float* b_out = (const float*)d_in[13];
  float* out = (float*)d_out;

  char* p = (char*)d_ws;
  float* h    = (float*)p;            p += 134217728;   // [4096][64][128] fp32
  short* wch  = (short*)p;            p += 131072;
  short* wcl  = (short*)p;            p += 131072;
  short* wuph = (short*)p;            p += 131072;
  short* wupl = (short*)p;            p += 131072;
  short* wdnh = (short*)p;            p += 65536;
  short* wdnl = (short*)p;            p += 65536;

  k_prep_w<<<2, 256, 0, stream>>>(wg, rk, wup, wdn, wch, wcl,
                                  wuph, wupl, wdnh, wdnl);
  k_init_h<<<(Bc*Sc*Ec)/256, 256, 0, stream>>>(x, w_in, b_in, h, Bc*Sc*Ec);
  for (int ib = 0; ib < 2; ib++) {
    k_scan4<<<Bc/16, 512, 0, stream>>>(h, wch + ib*32768, wcl + ib*32768,
                                       bcell + ib*512, ln1_w + ib*128, gn_w + ib*128);
    k_ffn4<<<(Bc*Sc)/64, 256, 0, stream>>>(h, ln2_w + ib*128,
                                           wuph + ib*32768, wupl + ib*32768,
                                           wdnh + ib*16384, wdnl + ib*16384);
  }
  k_out<<<Bc/4, 256, 0, stream>>>(h, postw, w_out, b_out, out, Bc);
}

// Round 9
// 580.453 us; speedup vs baseline: 6.4803x; 1.0599x over previous
//
#include <hip/hip_runtime.h>
#include <math.h>

#define Bc 4096
#define NHc 4
#define HDc 32
#define Ec 128
#define Sc 64
#define EPSc 1e-5f

using bf16x8 = __attribute__((ext_vector_type(8))) short;
using f32x4  = __attribute__((ext_vector_type(4))) float;

#define MFMA(a,b,c) __builtin_amdgcn_mfma_f32_16x16x32_bf16((a),(b),(c),0,0,0)
#define RCP(x) __builtin_amdgcn_rcpf(x)

__device__ __forceinline__ short f2bf(float f) {
  union { float f; unsigned u; } v; v.f = f;
  unsigned r = v.u + 0x7fffu + ((v.u >> 16) & 1u);
  return (short)(r >> 16);
}
__device__ __forceinline__ float bf2f(short s) {
  union { unsigned u; float f; } v; v.u = ((unsigned)(unsigned short)s) << 16;
  return v.f;
}

// exact-grade GELU via A&S 7.1.26 erf poly (|err| <= 1.5e-7)
__device__ __forceinline__ float gelu_exact(float g) {
  float x  = g * 0.70710678118654752f;
  float ax = fabsf(x);
  float t  = RCP(1.f + 0.3275911f*ax);
  float y  = t*(0.254829592f + t*(-0.284496736f + t*(1.421413741f
           + t*(-1.453152027f + t*1.061405429f))));
  float e  = __expf(-ax*ax);
  float er = 1.f - y*e;
  er = (x < 0.f) ? -er : er;
  return 0.5f*g*(1.f + er);
}

// ---------------- weight prep: fp32 -> hi/lo bf16 fragment order ----------------
__global__ void k_prep_w(const float* __restrict__ wg, const float* __restrict__ rk,
    const float* __restrict__ wup, const float* __restrict__ wdn,
    short* __restrict__ wch, short* __restrict__ wcl,
    short* __restrict__ wuph, short* __restrict__ wupl,
    short* __restrict__ wdnh, short* __restrict__ wdnl) {
  int ib = blockIdx.x;
  int tid = threadIdx.x;
  const float* wgp = wg + ib*16384;   // [4][NH][HD(o)][HD(d)]
  const float* rkp = rk + ib*16384;   // [NH][HD(d)][4][HD(o)]
  for (int idx = tid; idx < 32768; idx += 256) {
    int j = idx & 7, lane = (idx>>3)&63, kf = (idx>>9)&1, nt = (idx>>10)&7, hh = idx>>13;
    int n = nt*16 + (lane&15); int g = n>>5, o = n&31;
    int k = kf*32 + (lane>>4)*8 + j;
    float v = (k < 32) ? wgp[((g*NHc+hh)*HDc + o)*HDc + k]
                       : rkp[((hh*HDc + (k-32))*4 + g)*HDc + o];
    short hi16 = f2bf(v);
    wch[ib*32768 + idx] = hi16;
    wcl[ib*32768 + idx] = f2bf(v - bf2f(hi16));
  }
  const float* wupp = wup + ib*32768;  // [128][256]
  for (int idx = tid; idx < 32768; idx += 256) {
    int j = idx&7, lane=(idx>>3)&63, kf=(idx>>9)&3, nt = idx>>11;
    int n = nt*16 + (lane&15); int k = kf*32 + (lane>>4)*8 + j;
    float v = wupp[k*256 + n];
    short hi16 = f2bf(v);
    wuph[ib*32768 + idx] = hi16;
    wupl[ib*32768 + idx] = f2bf(v - bf2f(hi16));
  }
  const float* wdnp = wdn + ib*16384;  // [128][128]
  for (int idx = tid; idx < 16384; idx += 256) {
    int j = idx&7, lane=(idx>>3)&63, kf=(idx>>9)&3, nt = idx>>11;
    int n = nt*16+(lane&15); int k = kf*32+(lane>>4)*8+j;
    float v = wdnp[k*128 + n];
    short hi16 = f2bf(v);
    wdnh[ib*16384 + idx] = hi16;
    wdnl[ib*16384 + idx] = f2bf(v - bf2f(hi16));
  }
}

// ---------------- fused scan, 8-wave, 4-term split (fp32-exact gates) ----------------
// WG = 16 batches, 8 waves = (head hh, q-half p). 1 WG/CU, 2 waves/SIMD.
// first!=0: h rows computed from x@w_in+b_in in registers (init fused).
// Deferred mh_ln+residual alternates between p-waves by step parity.
__global__ __launch_bounds__(512, 2) void k_scan6(float* __restrict__ h,
    const float* __restrict__ x, const float* __restrict__ w_in,
    const float* __restrict__ b_in,
    const short* __restrict__ wch, const short* __restrict__ wcl,
    const float* __restrict__ bcell, const float* __restrict__ ln1w,
    const float* __restrict__ gnw, int first) {
  __shared__ short ybh[2][4][16][40];
  __shared__ short ybl[2][4][16][40];
  __shared__ float LNp[2][4][16][2];
  const int tid = threadIdx.x;
  const int wid = tid >> 6;
  const int hh = wid >> 1;
  const int p  = wid & 1;
  const int lane = tid & 63;
  const int l15 = lane & 15, hi = lane >> 4;
  const int bg = blockIdx.x;

  bf16x8 Bh[4][2], Bl[4][2];
  #pragma unroll
  for (int i = 0; i < 4; i++)
    #pragma unroll
    for (int kf = 0; kf < 2; kf++) {
      int off = ((hh*16 + (2*i+p)*2 + kf)*64 + lane)*8;
      Bh[i][kf] = *(const bf16x8*)(wch + off);
      Bl[i][kf] = *(const bf16x8*)(wcl + off);
    }

  float biasv[4];
  #pragma unroll
  for (int i = 0; i < 4; i++)
    biasv[i] = bcell[(i*NHc + hh)*HDc + p*16 + l15];
  float lnw[8], gwv[8];
  #pragma unroll
  for (int j = 0; j < 8; j++) {
    lnw[j] = ln1w[hh*32 + hi*8 + j];
    gwv[j] = gnw[hh*32 + hi*8 + j];
  }
  // init-fusion constants (used when first)
  float wv0[8], wv1[8], wv2[8], bi[8];
  if (first) {
    #pragma unroll
    for (int j = 0; j < 8; j++) {
      int col = hh*32 + hi*8 + j;
      wv0[j] = w_in[col]; wv1[j] = w_in[128+col]; wv2[j] = w_in[256+col];
      bi[j] = b_in[col];
    }
  }

  for (int i = tid; i < 4*16*40; i += 512) {
    ybh[1][0][0][i] = 0; ybl[1][0][0][i] = 0;
  }

  float cs[4], ns[4], ms[4];
  #pragma unroll
  for (int r = 0; r < 4; r++) { cs[r]=0.f; ns[r]=0.f; ms[r]=0.f; }

  float* hbase = h + ((size_t)(bg*16 + l15)*Sc)*Ec + hh*32 + hi*8;
  const float* xbase = x + ((size_t)(bg*16 + l15)*Sc)*3;
  float4 ha, hb;
  float xa0, xa1, xa2;
  if (first) {
    xa0 = xbase[0]; xa1 = xbase[1]; xa2 = xbase[2];
  } else {
    ha = *(const float4*)(hbase);
    hb = *(const float4*)(hbase + 4);
  }
  float hvprev[8];

  __syncthreads();

  for (int s = 0; s < Sc; s++) {
    float hv[8];
    if (first) {
      #pragma unroll
      for (int j = 0; j < 8; j++)
        hv[j] = bi[j] + xa0*wv0[j] + xa1*wv1[j] + xa2*wv2[j];
      if (s < 63) {
        xa0 = xbase[(s+1)*3]; xa1 = xbase[(s+1)*3+1]; xa2 = xbase[(s+1)*3+2];
      }
    } else {
      *(float4*)&hv[0] = ha; *(float4*)&hv[4] = hb;
      if (s < 63) {
        ha = *(const float4*)(hbase + (s+1)*Ec);
        hb = *(const float4*)(hbase + (s+1)*Ec + 4);
      }
    }
    // ---- LN1 partials ----
    float sum = 0.f, sq = 0.f;
    #pragma unroll
    for (int j = 0; j < 8; j++) { sum += hv[j]; sq += hv[j]*hv[j]; }
    sum += __shfl_xor(sum, 16); sq += __shfl_xor(sq, 16);
    sum += __shfl_xor(sum, 32); sq += __shfl_xor(sq, 32);
    if (p == 0 && hi == 0) { LNp[s&1][hh][l15][0] = sum; LNp[s&1][hh][l15][1] = sq; }
    __syncthreads();
    float tsum = LNp[s&1][0][l15][0] + LNp[s&1][1][l15][0]
               + LNp[s&1][2][l15][0] + LNp[s&1][3][l15][0];
    float tsq  = LNp[s&1][0][l15][1] + LNp[s&1][1][l15][1]
               + LNp[s&1][2][l15][1] + LNp[s&1][3][l15][1];
    float mu = tsum * (1.f/128.f);
    float rs = rsqrtf(tsq*(1.f/128.f) - mu*mu + EPSc);

    // ---- hn A-frag hi/lo (row = batch l15, k = hi*8+j) ----
    bf16x8 Ah, Al;
    #pragma unroll
    for (int j = 0; j < 8; j++) {
      float hn = (hv[j]-mu)*rs*lnw[j];
      short h16 = f2bf(hn);
      Ah[j] = h16;
      Al[j] = f2bf(hn - bf2f(h16));
    }
    const int sbY = (s&1)^1;
    bf16x8 Yh = *(const bf16x8*)&ybh[sbY][hh][l15][hi*8];
    bf16x8 Yl = *(const bf16x8*)&ybl[sbY][hh][l15][hi*8];

    // ---- deferred mh_ln + residual for step s-1 (parity-alternating wave) ----
    if (s && ((s & 1) == p)) {
      float y8[8], s2 = 0.f, q2 = 0.f;
      #pragma unroll
      for (int j = 0; j < 8; j++) {
        y8[j] = bf2f(Yh[j]) + bf2f(Yl[j]);
        s2 += y8[j]; q2 += y8[j]*y8[j];
      }
      s2 += __shfl_xor(s2, 16); q2 += __shfl_xor(q2, 16);
      s2 += __shfl_xor(s2, 32); q2 += __shfl_xor(q2, 32);
      float mu2 = s2 * (1.f/32.f);
      float rs2 = rsqrtf(q2*(1.f/32.f) - mu2*mu2 + EPSc);
      float4 o0, o1;
      o0.x = hvprev[0] + (y8[0]-mu2)*rs2*gwv[0];
      o0.y = hvprev[1] + (y8[1]-mu2)*rs2*gwv[1];
      o0.z = hvprev[2] + (y8[2]-mu2)*rs2*gwv[2];
      o0.w = hvprev[3] + (y8[3]-mu2)*rs2*gwv[3];
      o1.x = hvprev[4] + (y8[4]-mu2)*rs2*gwv[4];
      o1.y = hvprev[5] + (y8[5]-mu2)*rs2*gwv[5];
      o1.z = hvprev[6] + (y8[6]-mu2)*rs2*gwv[6];
      o1.w = hvprev[7] + (y8[7]-mu2)*rs2*gwv[7];
      *(float4*)(hbase + (size_t)(s-1)*Ec)     = o0;
      *(float4*)(hbase + (size_t)(s-1)*Ec + 4) = o1;
    }
    #pragma unroll
    for (int j = 0; j < 8; j++) hvprev[j] = hv[j];

    // ---- gates MFMA: 4 ntiles x 8 split terms (full hi/lo product) ----
    f32x4 acc[4];
    #pragma unroll
    for (int i = 0; i < 4; i++) {
      f32x4 c; c[0]=biasv[i]; c[1]=biasv[i]; c[2]=biasv[i]; c[3]=biasv[i];
      c = MFMA(Ah, Bh[i][0], c);
      c = MFMA(Ah, Bl[i][0], c);
      c = MFMA(Al, Bh[i][0], c);
      c = MFMA(Al, Bl[i][0], c);
      c = MFMA(Yh, Bh[i][1], c);
      c = MFMA(Yh, Bl[i][1], c);
      c = MFMA(Yl, Bh[i][1], c);
      acc[i] = MFMA(Yl, Bl[i][1], c);
    }

    // ---- cell update ----
    #pragma unroll
    for (int r = 0; r < 4; r++) {
      float iraw = acc[0][r];
      float fraw = acc[1][r];
      float zraw = acc[2][r];
      float oraw = acc[3][r];
      float ax  = fabsf(fraw);
      float lsg = fminf(fraw, 0.f) - __logf(1.f + __expf(-ax));
      float lfm = ms[r] + lsg;
      float mnew = (ns[r] == 0.f) ? iraw : fmaxf(iraw, lfm);
      float og = RCP(1.f + __expf(-oraw));
      float ig = __expf(iraw - mnew);
      float fg = __expf(lfm - mnew);
      float e2 = __expf(2.f*zraw);
      float th = 1.f - 2.f*RCP(e2 + 1.f);
      float cn = fg*cs[r] + ig*th;
      float nn = fg*ns[r] + ig;
      cs[r] = cn; ns[r] = nn; ms[r] = mnew;
      float y = og*cn*RCP(nn);
      short y16 = f2bf(y);
      ybh[s&1][hh][hi*4+r][p*16+l15] = y16;
      ybl[s&1][hh][hi*4+r][p*16+l15] = f2bf(y - bf2f(y16));
    }
  }

  // ---- epilogue: mh_ln + residual for s=63 (parity of s=64 -> p==0) ----
  __syncthreads();
  if (p == 0) {
    bf16x8 Yh = *(const bf16x8*)&ybh[(Sc-1)&1][hh][l15][hi*8];
    bf16x8 Yl = *(const bf16x8*)&ybl[(Sc-1)&1][hh][l15][hi*8];
    float y8[8], s2 = 0.f, q2 = 0.f;
    #pragma unroll
    for (int j = 0; j < 8; j++) {
      y8[j] = bf2f(Yh[j]) + bf2f(Yl[j]);
      s2 += y8[j]; q2 += y8[j]*y8[j];
    }
    s2 += __shfl_xor(s2, 16); q2 += __shfl_xor(q2, 16);
    s2 += __shfl_xor(s2, 32); q2 += __shfl_xor(q2, 32);
    float mu2 = s2 * (1.f/32.f);
    float rs2 = rsqrtf(q2*(1.f/32.f) - mu2*mu2 + EPSc);
    float4 o0, o1;
    o0.x = hvprev[0] + (y8[0]-mu2)*rs2*gwv[0];
    o0.y = hvprev[1] + (y8[1]-mu2)*rs2*gwv[1];
    o0.z = hvprev[2] + (y8[2]-mu2)*rs2*gwv[2];
    o0.w = hvprev[3] + (y8[3]-mu2)*rs2*gwv[3];
    o1.x = hvprev[4] + (y8[4]-mu2)*rs2*gwv[4];
    o1.y = hvprev[5] + (y8[5]-mu2)*rs2*gwv[5];
    o1.z = hvprev[6] + (y8[6]-mu2)*rs2*gwv[6];
    o1.w = hvprev[7] + (y8[7]-mu2)*rs2*gwv[7];
    *(float4*)(hbase + (size_t)(Sc-1)*Ec)     = o0;
    *(float4*)(hbase + (size_t)(Sc-1)*Ec + 4) = o1;
  }
}

// ---------------- fused FFN (fp32-grade): LN2 + up + GELU*up + down + residual ----
// Separate hi/lo LDS buffers: A-frag reads are direct b128 bf16x8 loads.
__global__ __launch_bounds__(256) void k_ffn4(float* __restrict__ h,
    const float* __restrict__ ln2w,
    const short* __restrict__ wuph, const short* __restrict__ wupl,
    const short* __restrict__ wdnh, const short* __restrict__ wdnl) {
  __shared__ short bufH[8192];   // [64 tok][128] hi, XOR-swizzled ^((row&7)<<4)
  __shared__ short bufL[8192];
  size_t tok0 = (size_t)blockIdx.x * 64;
  int tid = threadIdx.x;
  int wv = tid >> 6, lane = tid & 63, l15 = lane & 15, hi = lane >> 4;

  { // LN2 -> bufH/bufL
    int t = tid >> 2, sub = tid & 3;
    const float* row = h + (tok0 + t)*Ec + sub*32;
    float v[32];
    #pragma unroll
    for (int q = 0; q < 8; q++) *(float4*)&v[q*4] = *(const float4*)&row[q*4];
    float sum = 0.f, sq = 0.f;
    #pragma unroll
    for (int j = 0; j < 32; j++) { sum += v[j]; sq += v[j]*v[j]; }
    sum += __shfl_xor(sum,1); sq += __shfl_xor(sq,1);
    sum += __shfl_xor(sum,2); sq += __shfl_xor(sq,2);
    float mu = sum * (1.f/128.f);
    float rs = rsqrtf(sq*(1.f/128.f) - mu*mu + EPSc);
    #pragma unroll
    for (int q2 = 0; q2 < 4; q2++) {
      bf16x8 ph, pl;
      #pragma unroll
      for (int j = 0; j < 8; j++) {
        float hn = (v[q2*8+j]-mu)*rs*ln2w[sub*32+q2*8+j];
        short h16 = f2bf(hn);
        ph[j] = h16;
        pl[j] = f2bf(hn - bf2f(h16));
      }
      int byte = (t*256 + sub*64 + q2*16) ^ ((t&7)<<4);
      *(bf16x8*)((char*)bufH + byte) = ph;
      *(bf16x8*)((char*)bufL + byte) = pl;
    }
  }
  __syncthreads();

  // up GEMM
  f32x4 ag[2][4], au[2][4];
  #pragma unroll
  for (int p = 0; p < 2; p++)
    #pragma unroll
    for (int mt = 0; mt < 4; mt++)
      #pragma unroll
      for (int r = 0; r < 4; r++) { ag[p][mt][r]=0.f; au[p][mt][r]=0.f; }
  #pragma unroll 1
  for (int kf = 0; kf < 4; kf++) {
    bf16x8 Ah[4], Al[4];
    #pragma unroll
    for (int mt = 0; mt < 4; mt++) {
      int rw = mt*16 + l15;
      int byte = (rw*256 + kf*64 + hi*16) ^ ((rw&7)<<4);
      Ah[mt] = *(const bf16x8*)((const char*)bufH + byte);
      Al[mt] = *(const bf16x8*)((const char*)bufL + byte);
    }
    #pragma unroll
    for (int p = 0; p < 2; p++) {
      int gOff = (((2*wv+p)*4 + kf)*64 + lane)*8;
      int uOff = (((8+2*wv+p)*4 + kf)*64 + lane)*8;
      bf16x8 Bgh = *(const bf16x8*)(wuph + gOff);
      bf16x8 Bgl = *(const bf16x8*)(wupl + gOff);
      bf16x8 Buh = *(const bf16x8*)(wuph + uOff);
      bf16x8 Bul = *(const bf16x8*)(wupl + uOff);
      #pragma unroll
      for (int mt = 0; mt < 4; mt++) {
        ag[p][mt] = MFMA(Ah[mt], Bgh, ag[p][mt]);
        ag[p][mt] = MFMA(Ah[mt], Bgl, ag[p][mt]);
        ag[p][mt] = MFMA(Al[mt], Bgh, ag[p][mt]);
        au[p][mt] = MFMA(Ah[mt], Buh, au[p][mt]);
        au[p][mt] = MFMA(Ah[mt], Bul, au[p][mt]);
        au[p][mt] = MFMA(Al[mt], Buh, au[p][mt]);
      }
    }
  }
  __syncthreads();
  // exact GELU(gate)*up -> bufH/bufL
  #pragma unroll
  for (int p = 0; p < 2; p++)
    #pragma unroll
    for (int mt = 0; mt < 4; mt++)
      #pragma unroll
      for (int r = 0; r < 4; r++) {
        float g = ag[p][mt][r], u = au[p][mt][r];
        float a = gelu_exact(g)*u;
        int m = mt*16 + hi*4 + r, f = (2*wv+p)*16 + l15;
        int byte = (m*256 + f*2) ^ ((m&7)<<4);
        short a16 = f2bf(a);
        *(short*)((char*)bufH + byte) = a16;
        *(short*)((char*)bufL + byte) = f2bf(a - bf2f(a16));
      }
  __syncthreads();

  // down GEMM + residual
  f32x4 oc[2][4];
  #pragma unroll
  for (int p = 0; p < 2; p++)
    #pragma unroll
    for (int mt = 0; mt < 4; mt++)
      #pragma unroll
      for (int r = 0; r < 4; r++) oc[p][mt][r] = 0.f;
  #pragma unroll 1
  for (int kf = 0; kf < 4; kf++) {
    bf16x8 Ah[4], Al[4];
    #pragma unroll
    for (int mt = 0; mt < 4; mt++) {
      int rw = mt*16 + l15;
      int byte = (rw*256 + kf*64 + hi*16) ^ ((rw&7)<<4);
      Ah[mt] = *(const bf16x8*)((const char*)bufH + byte);
      Al[mt] = *(const bf16x8*)((const char*)bufL + byte);
    }
    #pragma unroll
    for (int p = 0; p < 2; p++) {
      int dOff = (((2*wv+p)*4 + kf)*64 + lane)*8;
      bf16x8 Bdh = *(const bf16x8*)(wdnh + dOff);
      bf16x8 Bdl = *(const bf16x8*)(wdnl + dOff);
      #pragma unroll
      for (int mt = 0; mt < 4; mt++) {
        oc[p][mt] = MFMA(Ah[mt], Bdh, oc[p][mt]);
        oc[p][mt] = MFMA(Ah[mt], Bdl, oc[p][mt]);
        oc[p][mt] = MFMA(Al[mt], Bdh, oc[p][mt]);
      }
    }
  }
  #pragma unroll
  for (int p = 0; p < 2; p++)
    #pragma unroll
    for (int mt = 0; mt < 4; mt++)
      #pragma unroll
      for (int r = 0; r < 4; r++) {
        int m = mt*16 + hi*4 + r, e = (2*wv+p)*16 + l15;
        float* hp = h + (tok0 + m)*Ec + e;
        *hp += oc[p][mt][r];
      }
}

// ---------------- output head ----------------
__global__ __launch_bounds__(256) void k_out(const float* __restrict__ h,
    const float* __restrict__ postw, const float* __restrict__ wout,
    const float* __restrict__ bout, float* __restrict__ out, int B) {
  int gw = (blockIdx.x * blockDim.x + threadIdx.x) >> 6;
  int lane = threadIdx.x & 63;
  if (gw >= B) return;
  const float* row = h + ((size_t)gw*Sc + (Sc-1))*Ec;
  float v0 = row[lane], v1 = row[64+lane];
  float sum = v0+v1, sq = v0*v0+v1*v1;
  #pragma unroll
  for (int m = 1; m < 64; m <<= 1) { sum += __shfl_xor(sum, m); sq += __shfl_xor(sq, m); }
  float mu = sum * (1.f/128.f);
  float rs = rsqrtf(sq*(1.f/128.f) - mu*mu + EPSc);
  float d = (v0-mu)*rs*postw[lane]*wout[lane] + (v1-mu)*rs*postw[64+lane]*wout[64+lane];
  #pragma unroll
  for (int m = 1; m < 64; m <<= 1) d += __shfl_xor(d, m);
  if (lane == 0) out[gw] = d + bout[0];
}

extern "C" void kernel_launch(void* const* d_in, const int* in_sizes, int n_in,
                              void* d_out, int out_size, void* d_ws, size_t ws_size,
                              hipStream_t stream) {
  const float* x     = (const float*)d_in[0];
  const float* w_in  = (const float*)d_in[1];
  const float* b_in  = (const float*)d_in[2];
  const float* ln1_w = (const float*)d_in[3];
  const float* wg    = (const float*)d_in[4];
  const float* rk    = (const float*)d_in[5];
  const float* bcell = (const float*)d_in[6];
  const float* gn_w  = (const float*)d_in[7];
  const float* ln2_w = (const float*)d_in[8];
  const float* wup   = (const float*)d_in[9];
  const float* wdn   = (const float*)d_in[10];
  const float* postw = (const float*)d_in[11];
  const float* w_out = (const float*)d_in[12];
  const float* b_out = (const float*)d_in[13];
  float* out = (float*)d_out;

  char* p = (char*)d_ws;
  float* h    = (float*)p;            p += 134217728;   // [4096][64][128] fp32
  short* wch  = (short*)p;            p += 131072;
  short* wcl  = (short*)p;            p += 131072;
  short* wuph = (short*)p;            p += 131072;
  short* wupl = (short*)p;            p += 131072;
  short* wdnh = (short*)p;            p += 65536;
  short* wdnl = (short*)p;            p += 65536;

  k_prep_w<<<2, 256, 0, stream>>>(wg, rk, wup, wdn, wch, wcl,
                                  wuph, wupl, wdnh, wdnl);
  for (int ib = 0; ib < 2; ib++) {
    k_scan6<<<Bc/16, 512, 0, stream>>>(h, x, w_in, b_in,
                                       wch + ib*32768, wcl + ib*32768,
                                       bcell + ib*512, ln1_w + ib*128, gn_w + ib*128,
                                       ib == 0 ? 1 : 0);
    k_ffn4<<<(Bc*Sc)/64, 256, 0, stream>>>(h, ln2_w + ib*128,
                                           wuph + ib*32768, wupl + ib*32768,
                                           wdnh + ib*16384, wdnl + ib*16384);
  }
  k_out<<<Bc/4, 256, 0, stream>>>(h, postw, w_out, b_out, out, Bc);
}

// Round 10
// 518.516 us; speedup vs baseline: 7.2544x; 1.1195x over previous
//
#include <hip/hip_runtime.h>
#include <math.h>

#define Bc 4096
#define NHc 4
#define HDc 32
#define Ec 128
#define Sc 64
#define EPSc 1e-5f

using bf16x8 = __attribute__((ext_vector_type(8))) short;
using f32x4  = __attribute__((ext_vector_type(4))) float;

#define MFMA(a,b,c) __builtin_amdgcn_mfma_f32_16x16x32_bf16((a),(b),(c),0,0,0)
#define RCP(x) __builtin_amdgcn_rcpf(x)

__device__ __forceinline__ short f2bf(float f) {
  union { float f; unsigned u; } v; v.f = f;
  unsigned r = v.u + 0x7fffu + ((v.u >> 16) & 1u);
  return (short)(r >> 16);
}
__device__ __forceinline__ float bf2f(short s) {
  union { unsigned u; float f; } v; v.u = ((unsigned)(unsigned short)s) << 16;
  return v.f;
}
__device__ __forceinline__ float asf(unsigned u) {
  union { unsigned u; float f; } v; v.u = u; return v.f;
}
__device__ __forceinline__ unsigned asu(float f) {
  union { float f; unsigned u; } v; v.f = f; return v.u;
}
// truncation-hi split: hi = top 16 bits, lo = RNE(v - hi). Pair error ~2^-18|v|.
__device__ __forceinline__ void splitT(float v, short& h16, short& l16) {
  unsigned u = asu(v);
  h16 = (short)(u >> 16);
  l16 = f2bf(v - asf(u & 0xffff0000u));
}

// exact-grade GELU via A&S 7.1.26 erf poly (|err| <= 1.5e-7)
__device__ __forceinline__ float gelu_exact(float g) {
  float x  = g * 0.70710678118654752f;
  float ax = fabsf(x);
  float t  = RCP(1.f + 0.3275911f*ax);
  float y  = t*(0.254829592f + t*(-0.284496736f + t*(1.421413741f
           + t*(-1.453152027f + t*1.061405429f))));
  float e  = __expf(-ax*ax);
  float er = 1.f - y*e;
  er = (x < 0.f) ? -er : er;
  return 0.5f*g*(1.f + er);
}

// ---------------- weight prep: fp32 -> hi/lo bf16 fragment order (64 blocks) ----------------
__global__ void k_prep_w(const float* __restrict__ wg, const float* __restrict__ rk,
    const float* __restrict__ wup, const float* __restrict__ wdn,
    short* __restrict__ wch, short* __restrict__ wcl,
    short* __restrict__ wuph, short* __restrict__ wupl,
    short* __restrict__ wdnh, short* __restrict__ wdnl) {
  int ib = blockIdx.x >> 5;
  int ck = blockIdx.x & 31;
  int tid = threadIdx.x;
  const float* wgp = wg + ib*16384;   // [4][NH][HD(o)][HD(d)]
  const float* rkp = rk + ib*16384;   // [NH][HD(d)][4][HD(o)]
  for (int idx = ck*1024 + tid; idx < ck*1024 + 1024; idx += 256) {
    int j = idx & 7, lane = (idx>>3)&63, kf = (idx>>9)&1, nt = (idx>>10)&7, hh = idx>>13;
    int n = nt*16 + (lane&15); int g = n>>5, o = n&31;
    int k = kf*32 + (lane>>4)*8 + j;
    float v = (k < 32) ? wgp[((g*NHc+hh)*HDc + o)*HDc + k]
                       : rkp[((hh*HDc + (k-32))*4 + g)*HDc + o];
    short hi16 = f2bf(v);
    wch[ib*32768 + idx] = hi16;
    wcl[ib*32768 + idx] = f2bf(v - bf2f(hi16));
  }
  const float* wupp = wup + ib*32768;  // [128][256]
  for (int idx = ck*1024 + tid; idx < ck*1024 + 1024; idx += 256) {
    int j = idx&7, lane=(idx>>3)&63, kf=(idx>>9)&3, nt = idx>>11;
    int n = nt*16 + (lane&15); int k = kf*32 + (lane>>4)*8 + j;
    float v = wupp[k*256 + n];
    short hi16 = f2bf(v);
    wuph[ib*32768 + idx] = hi16;
    wupl[ib*32768 + idx] = f2bf(v - bf2f(hi16));
  }
  const float* wdnp = wdn + ib*16384;  // [128][128]
  for (int idx = ck*512 + tid; idx < ck*512 + 512; idx += 256) {
    int j = idx&7, lane=(idx>>3)&63, kf=(idx>>9)&3, nt = idx>>11;
    int n = nt*16+(lane&15); int k = kf*32+(lane>>4)*8+j;
    float v = wdnp[k*128 + n];
    short hi16 = f2bf(v);
    wdnh[ib*16384 + idx] = hi16;
    wdnl[ib*16384 + idx] = f2bf(v - bf2f(hi16));
  }
}

// ---------------- fused scan, 8-wave, 4-term split (fp32-exact gates) ----------------
// WG = 16 batches, 8 waves = (head hh, q-half p). 1 WG/CU, 2 waves/SIMD.
__global__ __launch_bounds__(512, 2) void k_scan7(float* __restrict__ h,
    const float* __restrict__ x, const float* __restrict__ w_in,
    const float* __restrict__ b_in,
    const short* __restrict__ wch, const short* __restrict__ wcl,
    const float* __restrict__ bcell, const float* __restrict__ ln1w,
    const float* __restrict__ gnw, int first) {
  __shared__ short ybh[2][4][16][40];
  __shared__ short ybl[2][4][16][40];
  __shared__ float LNp[2][4][16][2];
  const int tid = threadIdx.x;
  const int wid = tid >> 6;
  const int hh = wid >> 1;
  const int p  = wid & 1;
  const int lane = tid & 63;
  const int l15 = lane & 15, hi = lane >> 4;
  const int bg = blockIdx.x;

  bf16x8 Bh[4][2], Bl[4][2];
  #pragma unroll
  for (int i = 0; i < 4; i++)
    #pragma unroll
    for (int kf = 0; kf < 2; kf++) {
      int off = ((hh*16 + (2*i+p)*2 + kf)*64 + lane)*8;
      Bh[i][kf] = *(const bf16x8*)(wch + off);
      Bl[i][kf] = *(const bf16x8*)(wcl + off);
    }

  float biasv[4];
  #pragma unroll
  for (int i = 0; i < 4; i++)
    biasv[i] = bcell[(i*NHc + hh)*HDc + p*16 + l15];
  float lnw[8], gwv[8];
  #pragma unroll
  for (int j = 0; j < 8; j++) {
    lnw[j] = ln1w[hh*32 + hi*8 + j];
    gwv[j] = gnw[hh*32 + hi*8 + j];
  }
  float wv0[8], wv1[8], wv2[8], bi[8];
  if (first) {
    #pragma unroll
    for (int j = 0; j < 8; j++) {
      int col = hh*32 + hi*8 + j;
      wv0[j] = w_in[col]; wv1[j] = w_in[128+col]; wv2[j] = w_in[256+col];
      bi[j] = b_in[col];
    }
  }

  for (int i = tid; i < 4*16*40; i += 512) {
    ybh[1][0][0][i] = 0; ybl[1][0][0][i] = 0;
  }

  float cs[4], ns[4], ms[4];
  #pragma unroll
  for (int r = 0; r < 4; r++) { cs[r]=0.f; ns[r]=0.f; ms[r]=0.f; }

  float* hbase = h + ((size_t)(bg*16 + l15)*Sc)*Ec + hh*32 + hi*8;
  const float* xbase = x + ((size_t)(bg*16 + l15)*Sc)*3;
  float4 ha, hb;
  float xa0, xa1, xa2;
  if (first) {
    xa0 = xbase[0]; xa1 = xbase[1]; xa2 = xbase[2];
  } else {
    ha = *(const float4*)(hbase);
    hb = *(const float4*)(hbase + 4);
  }
  float hvprev[8];

  __syncthreads();

  for (int s = 0; s < Sc; s++) {
    float hv[8];
    if (first) {
      #pragma unroll
      for (int j = 0; j < 8; j++)
        hv[j] = bi[j] + xa0*wv0[j] + xa1*wv1[j] + xa2*wv2[j];
      if (s < 63) {
        xa0 = xbase[(s+1)*3]; xa1 = xbase[(s+1)*3+1]; xa2 = xbase[(s+1)*3+2];
      }
    } else {
      *(float4*)&hv[0] = ha; *(float4*)&hv[4] = hb;
      if (s < 63) {
        ha = *(const float4*)(hbase + (s+1)*Ec);
        hb = *(const float4*)(hbase + (s+1)*Ec + 4);
      }
    }
    // ---- LN1 partials ----
    float sum = 0.f, sq = 0.f;
    #pragma unroll
    for (int j = 0; j < 8; j++) { sum += hv[j]; sq += hv[j]*hv[j]; }
    sum += __shfl_xor(sum, 16); sq += __shfl_xor(sq, 16);
    sum += __shfl_xor(sum, 32); sq += __shfl_xor(sq, 32);
    if (p == 0 && hi == 0) { LNp[s&1][hh][l15][0] = sum; LNp[s&1][hh][l15][1] = sq; }
    __syncthreads();
    float tsum = LNp[s&1][0][l15][0] + LNp[s&1][1][l15][0]
               + LNp[s&1][2][l15][0] + LNp[s&1][3][l15][0];
    float tsq  = LNp[s&1][0][l15][1] + LNp[s&1][1][l15][1]
               + LNp[s&1][2][l15][1] + LNp[s&1][3][l15][1];
    float mu = tsum * (1.f/128.f);
    float rs = rsqrtf(tsq*(1.f/128.f) - mu*mu + EPSc);

    // ---- hn A-frag hi/lo (RNE split — recurrent path keeps full accuracy) ----
    bf16x8 Ah, Al;
    #pragma unroll
    for (int j = 0; j < 8; j++) {
      float hn = (hv[j]-mu)*rs*lnw[j];
      short h16 = f2bf(hn);
      Ah[j] = h16;
      Al[j] = f2bf(hn - bf2f(h16));
    }
    const int sbY = (s&1)^1;
    bf16x8 Yh = *(const bf16x8*)&ybh[sbY][hh][l15][hi*8];
    bf16x8 Yl = *(const bf16x8*)&ybl[sbY][hh][l15][hi*8];

    // ---- deferred mh_ln + residual for step s-1 (parity-alternating wave) ----
    if (s && ((s & 1) == p)) {
      float y8[8], s2 = 0.f, q2 = 0.f;
      #pragma unroll
      for (int j = 0; j < 8; j++) {
        y8[j] = bf2f(Yh[j]) + bf2f(Yl[j]);
        s2 += y8[j]; q2 += y8[j]*y8[j];
      }
      s2 += __shfl_xor(s2, 16); q2 += __shfl_xor(q2, 16);
      s2 += __shfl_xor(s2, 32); q2 += __shfl_xor(q2, 32);
      float mu2 = s2 * (1.f/32.f);
      float rs2 = rsqrtf(q2*(1.f/32.f) - mu2*mu2 + EPSc);
      float4 o0, o1;
      o0.x = hvprev[0] + (y8[0]-mu2)*rs2*gwv[0];
      o0.y = hvprev[1] + (y8[1]-mu2)*rs2*gwv[1];
      o0.z = hvprev[2] + (y8[2]-mu2)*rs2*gwv[2];
      o0.w = hvprev[3] + (y8[3]-mu2)*rs2*gwv[3];
      o1.x = hvprev[4] + (y8[4]-mu2)*rs2*gwv[4];
      o1.y = hvprev[5] + (y8[5]-mu2)*rs2*gwv[5];
      o1.z = hvprev[6] + (y8[6]-mu2)*rs2*gwv[6];
      o1.w = hvprev[7] + (y8[7]-mu2)*rs2*gwv[7];
      *(float4*)(hbase + (size_t)(s-1)*Ec)     = o0;
      *(float4*)(hbase + (size_t)(s-1)*Ec + 4) = o1;
    }
    #pragma unroll
    for (int j = 0; j < 8; j++) hvprev[j] = hv[j];

    // ---- gates MFMA: 4 ntiles x 8 split terms ----
    f32x4 acc[4];
    #pragma unroll
    for (int i = 0; i < 4; i++) {
      f32x4 c; c[0]=biasv[i]; c[1]=biasv[i]; c[2]=biasv[i]; c[3]=biasv[i];
      c = MFMA(Ah, Bh[i][0], c);
      c = MFMA(Ah, Bl[i][0], c);
      c = MFMA(Al, Bh[i][0], c);
      c = MFMA(Al, Bl[i][0], c);
      c = MFMA(Yh, Bh[i][1], c);
      c = MFMA(Yh, Bl[i][1], c);
      c = MFMA(Yl, Bh[i][1], c);
      acc[i] = MFMA(Yl, Bl[i][1], c);
    }

    // ---- cell update (single-exp ig/fg) ----
    #pragma unroll
    for (int r = 0; r < 4; r++) {
      float iraw = acc[0][r];
      float fraw = acc[1][r];
      float zraw = acc[2][r];
      float oraw = acc[3][r];
      float ax  = fabsf(fraw);
      float lsg = fminf(fraw, 0.f) - __logf(1.f + __expf(-ax));
      float lfm = ms[r] + lsg;
      float diff = iraw - lfm;
      float emin = __expf(-fabsf(diff));
      bool cnd = (ns[r] == 0.f) | (diff >= 0.f);
      float mnew = cnd ? iraw : lfm;
      float ig = cnd ? 1.f : emin;
      float fg = cnd ? emin : 1.f;   // ns==0: fg multiplies cs=ns=0 (finite, exact)
      float og = RCP(1.f + __expf(-oraw));
      float e2 = __expf(2.f*zraw);
      float th = 1.f - 2.f*RCP(e2 + 1.f);
      float cn = fg*cs[r] + ig*th;
      float nn = fg*ns[r] + ig;
      cs[r] = cn; ns[r] = nn; ms[r] = mnew;
      float y = og*cn*RCP(nn);
      short y16 = f2bf(y);
      ybh[s&1][hh][hi*4+r][p*16+l15] = y16;
      ybl[s&1][hh][hi*4+r][p*16+l15] = f2bf(y - bf2f(y16));
    }
  }

  // ---- epilogue: mh_ln + residual for s=63 ----
  __syncthreads();
  if (p == 0) {
    bf16x8 Yh = *(const bf16x8*)&ybh[(Sc-1)&1][hh][l15][hi*8];
    bf16x8 Yl = *(const bf16x8*)&ybl[(Sc-1)&1][hh][l15][hi*8];
    float y8[8], s2 = 0.f, q2 = 0.f;
    #pragma unroll
    for (int j = 0; j < 8; j++) {
      y8[j] = bf2f(Yh[j]) + bf2f(Yl[j]);
      s2 += y8[j]; q2 += y8[j]*y8[j];
    }
    s2 += __shfl_xor(s2, 16); q2 += __shfl_xor(q2, 16);
    s2 += __shfl_xor(s2, 32); q2 += __shfl_xor(q2, 32);
    float mu2 = s2 * (1.f/32.f);
    float rs2 = rsqrtf(q2*(1.f/32.f) - mu2*mu2 + EPSc);
    float4 o0, o1;
    o0.x = hvprev[0] + (y8[0]-mu2)*rs2*gwv[0];
    o0.y = hvprev[1] + (y8[1]-mu2)*rs2*gwv[1];
    o0.z = hvprev[2] + (y8[2]-mu2)*rs2*gwv[2];
    o0.w = hvprev[3] + (y8[3]-mu2)*rs2*gwv[3];
    o1.x = hvprev[4] + (y8[4]-mu2)*rs2*gwv[4];
    o1.y = hvprev[5] + (y8[5]-mu2)*rs2*gwv[5];
    o1.z = hvprev[6] + (y8[6]-mu2)*rs2*gwv[6];
    o1.w = hvprev[7] + (y8[7]-mu2)*rs2*gwv[7];
    *(float4*)(hbase + (size_t)(Sc-1)*Ec)     = o0;
    *(float4*)(hbase + (size_t)(Sc-1)*Ec + 4) = o1;
  }
}

// ---------------- fused FFN (fp32-grade, trunc-hi splits) ----------------
__global__ __launch_bounds__(256) void k_ffn6(float* __restrict__ h,
    const float* __restrict__ ln2w,
    const short* __restrict__ wuph, const short* __restrict__ wupl,
    const short* __restrict__ wdnh, const short* __restrict__ wdnl) {
  __shared__ short bufH[8192];   // [64 tok][128] hi, XOR-swizzled ^((row&7)<<4)
  __shared__ short bufL[8192];
  size_t tok0 = (size_t)blockIdx.x * 64;
  int tid = threadIdx.x;
  int wv = tid >> 6, lane = tid & 63, l15 = lane & 15, hi = lane >> 4;

  { // LN2 -> bufH/bufL
    int t = tid >> 2, sub = tid & 3;
    const float* row = h + (tok0 + t)*Ec + sub*32;
    float v[32];
    #pragma unroll
    for (int q = 0; q < 8; q++) *(float4*)&v[q*4] = *(const float4*)&row[q*4];
    float sum = 0.f, sq = 0.f;
    #pragma unroll
    for (int j = 0; j < 32; j++) { sum += v[j]; sq += v[j]*v[j]; }
    sum += __shfl_xor(sum,1); sq += __shfl_xor(sq,1);
    sum += __shfl_xor(sum,2); sq += __shfl_xor(sq,2);
    float mu = sum * (1.f/128.f);
    float rs = rsqrtf(sq*(1.f/128.f) - mu*mu + EPSc);
    #pragma unroll
    for (int q2 = 0; q2 < 4; q2++) {
      bf16x8 ph, pl;
      #pragma unroll
      for (int j = 0; j < 8; j++) {
        float hn = (v[q2*8+j]-mu)*rs*ln2w[sub*32+q2*8+j];
        short h16, l16; splitT(hn, h16, l16);
        ph[j] = h16; pl[j] = l16;
      }
      int byte = (t*256 + sub*64 + q2*16) ^ ((t&7)<<4);
      *(bf16x8*)((char*)bufH + byte) = ph;
      *(bf16x8*)((char*)bufL + byte) = pl;
    }
  }
  __syncthreads();

  // up GEMM
  f32x4 ag[2][4], au[2][4];
  #pragma unroll
  for (int p = 0; p < 2; p++)
    #pragma unroll
    for (int mt = 0; mt < 4; mt++)
      #pragma unroll
      for (int r = 0; r < 4; r++) { ag[p][mt][r]=0.f; au[p][mt][r]=0.f; }
  #pragma unroll 1
  for (int kf = 0; kf < 4; kf++) {
    bf16x8 Ah[4], Al[4];
    #pragma unroll
    for (int mt = 0; mt < 4; mt++) {
      int rw = mt*16 + l15;
      int byte = (rw*256 + kf*64 + hi*16) ^ ((rw&7)<<4);
      Ah[mt] = *(const bf16x8*)((const char*)bufH + byte);
      Al[mt] = *(const bf16x8*)((const char*)bufL + byte);
    }
    #pragma unroll
    for (int p = 0; p < 2; p++) {
      int gOff = (((2*wv+p)*4 + kf)*64 + lane)*8;
      int uOff = (((8+2*wv+p)*4 + kf)*64 + lane)*8;
      bf16x8 Bgh = *(const bf16x8*)(wuph + gOff);
      bf16x8 Bgl = *(const bf16x8*)(wupl + gOff);
      bf16x8 Buh = *(const bf16x8*)(wuph + uOff);
      bf16x8 Bul = *(const bf16x8*)(wupl + uOff);
      #pragma unroll
      for (int mt = 0; mt < 4; mt++) {
        ag[p][mt] = MFMA(Ah[mt], Bgh, ag[p][mt]);
        ag[p][mt] = MFMA(Ah[mt], Bgl, ag[p][mt]);
        ag[p][mt] = MFMA(Al[mt], Bgh, ag[p][mt]);
        au[p][mt] = MFMA(Ah[mt], Buh, au[p][mt]);
        au[p][mt] = MFMA(Ah[mt], Bul, au[p][mt]);
        au[p][mt] = MFMA(Al[mt], Buh, au[p][mt]);
      }
    }
  }
  __syncthreads();
  // exact GELU(gate)*up -> bufH/bufL
  #pragma unroll
  for (int p = 0; p < 2; p++)
    #pragma unroll
    for (int mt = 0; mt < 4; mt++)
      #pragma unroll
      for (int r = 0; r < 4; r++) {
        float g = ag[p][mt][r], u = au[p][mt][r];
        float a = gelu_exact(g)*u;
        int m = mt*16 + hi*4 + r, f = (2*wv+p)*16 + l15;
        int byte = (m*256 + f*2) ^ ((m&7)<<4);
        short a16, al16; splitT(a, a16, al16);
        *(short*)((char*)bufH + byte) = a16;
        *(short*)((char*)bufL + byte) = al16;
      }
  __syncthreads();

  // down GEMM + residual
  f32x4 oc[2][4];
  #pragma unroll
  for (int p = 0; p < 2; p++)
    #pragma unroll
    for (int mt = 0; mt < 4; mt++)
      #pragma unroll
      for (int r = 0; r < 4; r++) oc[p][mt][r] = 0.f;
  #pragma unroll 1
  for (int kf = 0; kf < 4; kf++) {
    bf16x8 Ah[4], Al[4];
    #pragma unroll
    for (int mt = 0; mt < 4; mt++) {
      int rw = mt*16 + l15;
      int byte = (rw*256 + kf*64 + hi*16) ^ ((rw&7)<<4);
      Ah[mt] = *(const bf16x8*)((const char*)bufH + byte);
      Al[mt] = *(const bf16x8*)((const char*)bufL + byte);
    }
    #pragma unroll
    for (int p = 0; p < 2; p++) {
      int dOff = (((2*wv+p)*4 + kf)*64 + lane)*8;
      bf16x8 Bdh = *(const bf16x8*)(wdnh + dOff);
      bf16x8 Bdl = *(const bf16x8*)(wdnl + dOff);
      #pragma unroll
      for (int mt = 0; mt < 4; mt++) {
        oc[p][mt] = MFMA(Ah[mt], Bdh, oc[p][mt]);
        oc[p][mt] = MFMA(Ah[mt], Bdl, oc[p][mt]);
        oc[p][mt] = MFMA(Al[mt], Bdh, oc[p][mt]);
      }
    }
  }
  #pragma unroll
  for (int p = 0; p < 2; p++)
    #pragma unroll
    for (int mt = 0; mt < 4; mt++)
      #pragma unroll
      for (int r = 0; r < 4; r++) {
        int m = mt*16 + hi*4 + r, e = (2*wv+p)*16 + l15;
        float* hp = h + (tok0 + m)*Ec + e;
        *hp += oc[p][mt][r];
      }
}

// ---------------- output head ----------------
__global__ __launch_bounds__(256) void k_out(const float* __restrict__ h,
    const float* __restrict__ postw, const float* __restrict__ wout,
    const float* __restrict__ bout, float* __restrict__ out, int B) {
  int gw = (blockIdx.x * blockDim.x + threadIdx.x) >> 6;
  int lane = threadIdx.x & 63;
  if (gw >= B) return;
  const float* row = h + ((size_t)gw*Sc + (Sc-1))*Ec;
  float v0 = row[lane], v1 = row[64+lane];
  float sum = v0+v1, sq = v0*v0+v1*v1;
  #pragma unroll
  for (int m = 1; m < 64; m <<= 1) { sum += __shfl_xor(sum, m); sq += __shfl_xor(sq, m); }
  float mu = sum * (1.f/128.f);
  float rs = rsqrtf(sq*(1.f/128.f) - mu*mu + EPSc);
  float d = (v0-mu)*rs*postw[lane]*wout[lane] + (v1-mu)*rs*postw[64+lane]*wout[64+lane];
  #pragma unroll
  for (int m = 1; m < 64; m <<= 1) d += __shfl_xor(d, m);
  if (lane == 0) out[gw] = d + bout[0];
}

extern "C" void kernel_launch(void* const* d_in, const int* in_sizes, int n_in,
                              void* d_out, int out_size, void* d_ws, size_t ws_size,
                              hipStream_t stream) {
  const float* x     = (const float*)d_in[0];
  const float* w_in  = (const float*)d_in[1];
  const float* b_in  = (const float*)d_in[2];
  const float* ln1_w = (const float*)d_in[3];
  const float* wg    = (const float*)d_in[4];
  const float* rk    = (const float*)d_in[5];
  const float* bcell = (const float*)d_in[6];
  const float* gn_w  = (const float*)d_in[7];
  const float* ln2_w = (const float*)d_in[8];
  const float* wup   = (const float*)d_in[9];
  const float* wdn   = (const float*)d_in[10];
  const float* postw = (const float*)d_in[11];
  const float* w_out = (const float*)d_in[12];
  const float* b_out = (const float*)d_in[13];
  float* out = (float*)d_out;

  char* p = (char*)d_ws;
  float* h    = (float*)p;            p += 134217728;   // [4096][64][128] fp32
  short* wch  = (short*)p;            p += 131072;
  short* wcl  = (short*)p;            p += 131072;
  short* wuph = (short*)p;            p += 131072;
  short* wupl = (short*)p;            p += 131072;
  short* wdnh = (short*)p;            p += 65536;
  short* wdnl = (short*)p;            p += 65536;

  k_prep_w<<<64, 256, 0, stream>>>(wg, rk, wup, wdn, wch, wcl,
                                   wuph, wupl, wdnh, wdnl);
  for (int ib = 0; ib < 2; ib++) {
    k_scan7<<<Bc/16, 512, 0, stream>>>(h, x, w_in, b_in,
                                       wch + ib*32768, wcl + ib*32768,
                                       bcell + ib*512, ln1_w + ib*128, gn_w + ib*128,
                                       ib == 0 ? 1 : 0);
    k_ffn6<<<(Bc*Sc)/64, 256, 0, stream>>>(h, ln2_w + ib*128,
                                           wuph + ib*32768, wupl + ib*32768,
                                           wdnh + ib*16384, wdnl + ib*16384);
  }
  k_out<<<Bc/4, 256, 0, stream>>>(h, postw, w_out, b_out, out, Bc);
}

// Round 13
// 518.181 us; speedup vs baseline: 7.2591x; 1.0006x over previous
//
#include <hip/hip_runtime.h>
#include <math.h>

#define Bc 4096
#define NHc 4
#define HDc 32
#define Ec 128
#define Sc 64
#define EPSc 1e-5f

using bf16x8 = __attribute__((ext_vector_type(8))) short;
using f32x4  = __attribute__((ext_vector_type(4))) float;

#define MFMA(a,b,c) __builtin_amdgcn_mfma_f32_16x16x32_bf16((a),(b),(c),0,0,0)
#define RCP(x) __builtin_amdgcn_rcpf(x)

__device__ __forceinline__ short f2bf(float f) {
  union { float f; unsigned u; } v; v.f = f;
  unsigned r = v.u + 0x7fffu + ((v.u >> 16) & 1u);
  return (short)(r >> 16);
}
__device__ __forceinline__ float bf2f(short s) {
  union { unsigned u; float f; } v; v.u = ((unsigned)(unsigned short)s) << 16;
  return v.f;
}
__device__ __forceinline__ float asf(unsigned u) {
  union { unsigned u; float f; } v; v.u = u; return v.f;
}
__device__ __forceinline__ unsigned asu(float f) {
  union { float f; unsigned u; } v; v.f = f; return v.u;
}
// truncation-hi split: hi = top 16 bits, lo = RNE(v - hi). Pair error ~2^-18|v|.
__device__ __forceinline__ void splitT(float v, short& h16, short& l16) {
  unsigned u = asu(v);
  h16 = (short)(u >> 16);
  l16 = f2bf(v - asf(u & 0xffff0000u));
}

// exact-grade GELU via A&S 7.1.26 erf poly (|err| <= 1.5e-7)
__device__ __forceinline__ float gelu_exact(float g) {
  float x  = g * 0.70710678118654752f;
  float ax = fabsf(x);
  float t  = RCP(1.f + 0.3275911f*ax);
  float y  = t*(0.254829592f + t*(-0.284496736f + t*(1.421413741f
           + t*(-1.453152027f + t*1.061405429f))));
  float e  = __expf(-ax*ax);
  float er = 1.f - y*e;
  er = (x < 0.f) ? -er : er;
  return 0.5f*g*(1.f + er);
}

// ---------------- weight prep: fp32 -> hi/lo bf16 fragment order (64 blocks) ----------------
__global__ void k_prep_w(const float* __restrict__ wg, const float* __restrict__ rk,
    const float* __restrict__ wup, const float* __restrict__ wdn,
    short* __restrict__ wch, short* __restrict__ wcl,
    short* __restrict__ wuph, short* __restrict__ wupl,
    short* __restrict__ wdnh, short* __restrict__ wdnl) {
  int ib = blockIdx.x >> 5;
  int ck = blockIdx.x & 31;
  int tid = threadIdx.x;
  const float* wgp = wg + ib*16384;   // [4][NH][HD(o)][HD(d)]
  const float* rkp = rk + ib*16384;   // [NH][HD(d)][4][HD(o)]
  for (int idx = ck*1024 + tid; idx < ck*1024 + 1024; idx += 256) {
    int j = idx & 7, lane = (idx>>3)&63, kf = (idx>>9)&1, nt = (idx>>10)&7, hh = idx>>13;
    int n = nt*16 + (lane&15); int g = n>>5, o = n&31;
    int k = kf*32 + (lane>>4)*8 + j;
    float v = (k < 32) ? wgp[((g*NHc+hh)*HDc + o)*HDc + k]
                       : rkp[((hh*HDc + (k-32))*4 + g)*HDc + o];
    short hi16 = f2bf(v);
    wch[ib*32768 + idx] = hi16;
    wcl[ib*32768 + idx] = f2bf(v - bf2f(hi16));
  }
  const float* wupp = wup + ib*32768;  // [128][256]
  for (int idx = ck*1024 + tid; idx < ck*1024 + 1024; idx += 256) {
    int j = idx&7, lane=(idx>>3)&63, kf=(idx>>9)&3, nt = idx>>11;
    int n = nt*16 + (lane&15); int k = kf*32 + (lane>>4)*8 + j;
    float v = wupp[k*256 + n];
    short hi16 = f2bf(v);
    wuph[ib*32768 + idx] = hi16;
    wupl[ib*32768 + idx] = f2bf(v - bf2f(hi16));
  }
  const float* wdnp = wdn + ib*16384;  // [128][128]
  for (int idx = ck*512 + tid; idx < ck*512 + 512; idx += 256) {
    int j = idx&7, lane=(idx>>3)&63, kf=(idx>>9)&3, nt = idx>>11;
    int n = nt*16+(lane&15); int k = kf*32+(lane>>4)*8+j;
    float v = wdnp[k*128 + n];
    short hi16 = f2bf(v);
    wdnh[ib*16384 + idx] = hi16;
    wdnl[ib*16384 + idx] = f2bf(v - bf2f(hi16));
  }
}

// ---------------- fused scan, 8-wave, 4-term split (fp32-exact gates) ----------------
// WG = 16 batches, 8 waves = (head hh, q-half p). 1 WG/CU, 2 waves/SIMD.
__global__ __launch_bounds__(512, 2) void k_scan7(float* __restrict__ h,
    const float* __restrict__ x, const float* __restrict__ w_in,
    const float* __restrict__ b_in,
    const short* __restrict__ wch, const short* __restrict__ wcl,
    const float* __restrict__ bcell, const float* __restrict__ ln1w,
    const float* __restrict__ gnw, int first) {
  __shared__ short ybh[2][4][16][40];
  __shared__ short ybl[2][4][16][40];
  __shared__ float LNp[2][4][16][2];
  const int tid = threadIdx.x;
  const int wid = tid >> 6;
  const int hh = wid >> 1;
  const int p  = wid & 1;
  const int lane = tid & 63;
  const int l15 = lane & 15, hi = lane >> 4;
  const int bg = blockIdx.x;

  bf16x8 Bh[4][2], Bl[4][2];
  #pragma unroll
  for (int i = 0; i < 4; i++)
    #pragma unroll
    for (int kf = 0; kf < 2; kf++) {
      int off = ((hh*16 + (2*i+p)*2 + kf)*64 + lane)*8;
      Bh[i][kf] = *(const bf16x8*)(wch + off);
      Bl[i][kf] = *(const bf16x8*)(wcl + off);
    }

  float biasv[4];
  #pragma unroll
  for (int i = 0; i < 4; i++)
    biasv[i] = bcell[(i*NHc + hh)*HDc + p*16 + l15];
  float lnw[8], gwv[8];
  #pragma unroll
  for (int j = 0; j < 8; j++) {
    lnw[j] = ln1w[hh*32 + hi*8 + j];
    gwv[j] = gnw[hh*32 + hi*8 + j];
  }
  float wv0[8], wv1[8], wv2[8], bi[8];
  if (first) {
    #pragma unroll
    for (int j = 0; j < 8; j++) {
      int col = hh*32 + hi*8 + j;
      wv0[j] = w_in[col]; wv1[j] = w_in[128+col]; wv2[j] = w_in[256+col];
      bi[j] = b_in[col];
    }
  }

  for (int i = tid; i < 4*16*40; i += 512) {
    ybh[1][0][0][i] = 0; ybl[1][0][0][i] = 0;
  }

  float cs[4], ns[4], ms[4];
  #pragma unroll
  for (int r = 0; r < 4; r++) { cs[r]=0.f; ns[r]=0.f; ms[r]=0.f; }

  float* hbase = h + ((size_t)(bg*16 + l15)*Sc)*Ec + hh*32 + hi*8;
  const float* xbase = x + ((size_t)(bg*16 + l15)*Sc)*3;
  float4 ha, hb;
  float xa0, xa1, xa2;
  if (first) {
    xa0 = xbase[0]; xa1 = xbase[1]; xa2 = xbase[2];
  } else {
    ha = *(const float4*)(hbase);
    hb = *(const float4*)(hbase + 4);
  }
  float hvprev[8];

  __syncthreads();

  for (int s = 0; s < Sc; s++) {
    float hv[8];
    if (first) {
      #pragma unroll
      for (int j = 0; j < 8; j++)
        hv[j] = bi[j] + xa0*wv0[j] + xa1*wv1[j] + xa2*wv2[j];
      if (s < 63) {
        xa0 = xbase[(s+1)*3]; xa1 = xbase[(s+1)*3+1]; xa2 = xbase[(s+1)*3+2];
      }
    } else {
      *(float4*)&hv[0] = ha; *(float4*)&hv[4] = hb;
      if (s < 63) {
        ha = *(const float4*)(hbase + (s+1)*Ec);
        hb = *(const float4*)(hbase + (s+1)*Ec + 4);
      }
    }
    // ---- LN1 partials ----
    float sum = 0.f, sq = 0.f;
    #pragma unroll
    for (int j = 0; j < 8; j++) { sum += hv[j]; sq += hv[j]*hv[j]; }
    sum += __shfl_xor(sum, 16); sq += __shfl_xor(sq, 16);
    sum += __shfl_xor(sum, 32); sq += __shfl_xor(sq, 32);
    if (p == 0 && hi == 0) { LNp[s&1][hh][l15][0] = sum; LNp[s&1][hh][l15][1] = sq; }
    __syncthreads();
    float tsum = LNp[s&1][0][l15][0] + LNp[s&1][1][l15][0]
               + LNp[s&1][2][l15][0] + LNp[s&1][3][l15][0];
    float tsq  = LNp[s&1][0][l15][1] + LNp[s&1][1][l15][1]
               + LNp[s&1][2][l15][1] + LNp[s&1][3][l15][1];
    float mu = tsum * (1.f/128.f);
    float rs = rsqrtf(tsq*(1.f/128.f) - mu*mu + EPSc);

    // ---- hn A-frag hi/lo (RNE split — recurrent path keeps full accuracy) ----
    bf16x8 Ah, Al;
    #pragma unroll
    for (int j = 0; j < 8; j++) {
      float hn = (hv[j]-mu)*rs*lnw[j];
      short h16 = f2bf(hn);
      Ah[j] = h16;
      Al[j] = f2bf(hn - bf2f(h16));
    }
    const int sbY = (s&1)^1;
    bf16x8 Yh = *(const bf16x8*)&ybh[sbY][hh][l15][hi*8];
    bf16x8 Yl = *(const bf16x8*)&ybl[sbY][hh][l15][hi*8];

    // ---- deferred mh_ln + residual for step s-1 (parity-alternating wave) ----
    if (s && ((s & 1) == p)) {
      float y8[8], s2 = 0.f, q2 = 0.f;
      #pragma unroll
      for (int j = 0; j < 8; j++) {
        y8[j] = bf2f(Yh[j]) + bf2f(Yl[j]);
        s2 += y8[j]; q2 += y8[j]*y8[j];
      }
      s2 += __shfl_xor(s2, 16); q2 += __shfl_xor(q2, 16);
      s2 += __shfl_xor(s2, 32); q2 += __shfl_xor(q2, 32);
      float mu2 = s2 * (1.f/32.f);
      float rs2 = rsqrtf(q2*(1.f/32.f) - mu2*mu2 + EPSc);
      float4 o0, o1;
      o0.x = hvprev[0] + (y8[0]-mu2)*rs2*gwv[0];
      o0.y = hvprev[1] + (y8[1]-mu2)*rs2*gwv[1];
      o0.z = hvprev[2] + (y8[2]-mu2)*rs2*gwv[2];
      o0.w = hvprev[3] + (y8[3]-mu2)*rs2*gwv[3];
      o1.x = hvprev[4] + (y8[4]-mu2)*rs2*gwv[4];
      o1.y = hvprev[5] + (y8[5]-mu2)*rs2*gwv[5];
      o1.z = hvprev[6] + (y8[6]-mu2)*rs2*gwv[6];
      o1.w = hvprev[7] + (y8[7]-mu2)*rs2*gwv[7];
      *(float4*)(hbase + (size_t)(s-1)*Ec)     = o0;
      *(float4*)(hbase + (size_t)(s-1)*Ec + 4) = o1;
    }
    #pragma unroll
    for (int j = 0; j < 8; j++) hvprev[j] = hv[j];

    // ---- gates MFMA: 4 ntiles x 8 split terms ----
    f32x4 acc[4];
    #pragma unroll
    for (int i = 0; i < 4; i++) {
      f32x4 c; c[0]=biasv[i]; c[1]=biasv[i]; c[2]=biasv[i]; c[3]=biasv[i];
      c = MFMA(Ah, Bh[i][0], c);
      c = MFMA(Ah, Bl[i][0], c);
      c = MFMA(Al, Bh[i][0], c);
      c = MFMA(Al, Bl[i][0], c);
      c = MFMA(Yh, Bh[i][1], c);
      c = MFMA(Yh, Bl[i][1], c);
      c = MFMA(Yl, Bh[i][1], c);
      acc[i] = MFMA(Yl, Bl[i][1], c);
    }

    // ---- cell update (single-exp ig/fg) ----
    #pragma unroll
    for (int r = 0; r < 4; r++) {
      float iraw = acc[0][r];
      float fraw = acc[1][r];
      float zraw = acc[2][r];
      float oraw = acc[3][r];
      float ax  = fabsf(fraw);
      float lsg = fminf(fraw, 0.f) - __logf(1.f + __expf(-ax));
      float lfm = ms[r] + lsg;
      float diff = iraw - lfm;
      float emin = __expf(-fabsf(diff));
      bool cnd = (ns[r] == 0.f) | (diff >= 0.f);
      float mnew = cnd ? iraw : lfm;
      float ig = cnd ? 1.f : emin;
      float fg = cnd ? emin : 1.f;
      float og = RCP(1.f + __expf(-oraw));
      float e2 = __expf(2.f*zraw);
      float th = 1.f - 2.f*RCP(e2 + 1.f);
      float cn = fg*cs[r] + ig*th;
      float nn = fg*ns[r] + ig;
      cs[r] = cn; ns[r] = nn; ms[r] = mnew;
      float y = og*cn*RCP(nn);
      short y16 = f2bf(y);
      ybh[s&1][hh][hi*4+r][p*16+l15] = y16;
      ybl[s&1][hh][hi*4+r][p*16+l15] = f2bf(y - bf2f(y16));
    }
  }

  // ---- epilogue: mh_ln + residual for s=63 ----
  __syncthreads();
  if (p == 0) {
    bf16x8 Yh = *(const bf16x8*)&ybh[(Sc-1)&1][hh][l15][hi*8];
    bf16x8 Yl = *(const bf16x8*)&ybl[(Sc-1)&1][hh][l15][hi*8];
    float y8[8], s2 = 0.f, q2 = 0.f;
    #pragma unroll
    for (int j = 0; j < 8; j++) {
      y8[j] = bf2f(Yh[j]) + bf2f(Yl[j]);
      s2 += y8[j]; q2 += y8[j]*y8[j];
    }
    s2 += __shfl_xor(s2, 16); q2 += __shfl_xor(q2, 16);
    s2 += __shfl_xor(s2, 32); q2 += __shfl_xor(q2, 32);
    float mu2 = s2 * (1.f/32.f);
    float rs2 = rsqrtf(q2*(1.f/32.f) - mu2*mu2 + EPSc);
    float4 o0, o1;
    o0.x = hvprev[0] + (y8[0]-mu2)*rs2*gwv[0];
    o0.y = hvprev[1] + (y8[1]-mu2)*rs2*gwv[1];
    o0.z = hvprev[2] + (y8[2]-mu2)*rs2*gwv[2];
    o0.w = hvprev[3] + (y8[3]-mu2)*rs2*gwv[3];
    o1.x = hvprev[4] + (y8[4]-mu2)*rs2*gwv[4];
    o1.y = hvprev[5] + (y8[5]-mu2)*rs2*gwv[5];
    o1.z = hvprev[6] + (y8[6]-mu2)*rs2*gwv[6];
    o1.w = hvprev[7] + (y8[7]-mu2)*rs2*gwv[7];
    *(float4*)(hbase + (size_t)(Sc-1)*Ec)     = o0;
    *(float4*)(hbase + (size_t)(Sc-1)*Ec + 4) = o1;
  }
}

// ---------------- fused FFN (fp32-grade, trunc-hi splits) ----------------
__global__ __launch_bounds__(256) void k_ffn6(float* __restrict__ h,
    const float* __restrict__ ln2w,
    const short* __restrict__ wuph, const short* __restrict__ wupl,
    const short* __restrict__ wdnh, const short* __restrict__ wdnl) {
  __shared__ short bufH[8192];   // [64 tok][128] hi, XOR-swizzled ^((row&7)<<4)
  __shared__ short bufL[8192];
  size_t tok0 = (size_t)blockIdx.x * 64;
  int tid = threadIdx.x;
  int wv = tid >> 6, lane = tid & 63, l15 = lane & 15, hi = lane >> 4;

  { // LN2 -> bufH/bufL
    int t = tid >> 2, sub = tid & 3;
    const float* row = h + (tok0 + t)*Ec + sub*32;
    float v[32];
    #pragma unroll
    for (int q = 0; q < 8; q++) *(float4*)&v[q*4] = *(const float4*)&row[q*4];
    float sum = 0.f, sq = 0.f;
    #pragma unroll
    for (int j = 0; j < 32; j++) { sum += v[j]; sq += v[j]*v[j]; }
    sum += __shfl_xor(sum,1); sq += __shfl_xor(sq,1);
    sum += __shfl_xor(sum,2); sq += __shfl_xor(sq,2);
    float mu = sum * (1.f/128.f);
    float rs = rsqrtf(sq*(1.f/128.f) - mu*mu + EPSc);
    #pragma unroll
    for (int q2 = 0; q2 < 4; q2++) {
      bf16x8 ph, pl;
      #pragma unroll
      for (int j = 0; j < 8; j++) {
        float hn = (v[q2*8+j]-mu)*rs*ln2w[sub*32+q2*8+j];
        short h16, l16; splitT(hn, h16, l16);
        ph[j] = h16; pl[j] = l16;
      }
      int byte = (t*256 + sub*64 + q2*16) ^ ((t&7)<<4);
      *(bf16x8*)((char*)bufH + byte) = ph;
      *(bf16x8*)((char*)bufL + byte) = pl;
    }
  }
  __syncthreads();

  // up GEMM
  f32x4 ag[2][4], au[2][4];
  #pragma unroll
  for (int p = 0; p < 2; p++)
    #pragma unroll
    for (int mt = 0; mt < 4; mt++)
      #pragma unroll
      for (int r = 0; r < 4; r++) { ag[p][mt][r]=0.f; au[p][mt][r]=0.f; }
  #pragma unroll 1
  for (int kf = 0; kf < 4; kf++) {
    bf16x8 Ah[4], Al[4];
    #pragma unroll
    for (int mt = 0; mt < 4; mt++) {
      int rw = mt*16 + l15;
      int byte = (rw*256 + kf*64 + hi*16) ^ ((rw&7)<<4);
      Ah[mt] = *(const bf16x8*)((const char*)bufH + byte);
      Al[mt] = *(const bf16x8*)((const char*)bufL + byte);
    }
    #pragma unroll
    for (int p = 0; p < 2; p++) {
      int gOff = (((2*wv+p)*4 + kf)*64 + lane)*8;
      int uOff = (((8+2*wv+p)*4 + kf)*64 + lane)*8;
      bf16x8 Bgh = *(const bf16x8*)(wuph + gOff);
      bf16x8 Bgl = *(const bf16x8*)(wupl + gOff);
      bf16x8 Buh = *(const bf16x8*)(wuph + uOff);
      bf16x8 Bul = *(const bf16x8*)(wupl + uOff);
      #pragma unroll
      for (int mt = 0; mt < 4; mt++) {
        ag[p][mt] = MFMA(Ah[mt], Bgh, ag[p][mt]);
        ag[p][mt] = MFMA(Ah[mt], Bgl, ag[p][mt]);
        ag[p][mt] = MFMA(Al[mt], Bgh, ag[p][mt]);
        au[p][mt] = MFMA(Ah[mt], Buh, au[p][mt]);
        au[p][mt] = MFMA(Ah[mt], Bul, au[p][mt]);
        au[p][mt] = MFMA(Al[mt], Buh, au[p][mt]);
      }
    }
  }
  __syncthreads();
  // exact GELU(gate)*up -> bufH/bufL
  #pragma unroll
  for (int p = 0; p < 2; p++)
    #pragma unroll
    for (int mt = 0; mt < 4; mt++)
      #pragma unroll
      for (int r = 0; r < 4; r++) {
        float g = ag[p][mt][r], u = au[p][mt][r];
        float a = gelu_exact(g)*u;
        int m = mt*16 + hi*4 + r, f = (2*wv+p)*16 + l15;
        int byte = (m*256 + f*2) ^ ((m&7)<<4);
        short a16, al16; splitT(a, a16, al16);
        *(short*)((char*)bufH + byte) = a16;
        *(short*)((char*)bufL + byte) = al16;
      }
  __syncthreads();

  // down GEMM + residual
  f32x4 oc[2][4];
  #pragma unroll
  for (int p = 0; p < 2; p++)
    #pragma unroll
    for (int mt = 0; mt < 4; mt++)
      #pragma unroll
      for (int r = 0; r < 4; r++) oc[p][mt][r] = 0.f;
  #pragma unroll 1
  for (int kf = 0; kf < 4; kf++) {
    bf16x8 Ah[4], Al[4];
    #pragma unroll
    for (int mt = 0; mt < 4; mt++) {
      int rw = mt*16 + l15;
      int byte = (rw*256 + kf*64 + hi*16) ^ ((rw&7)<<4);
      Ah[mt] = *(const bf16x8*)((const char*)bufH + byte);
      Al[mt] = *(const bf16x8*)((const char*)bufL + byte);
    }
    #pragma unroll
    for (int p = 0; p < 2; p++) {
      int dOff = (((2*wv+p)*4 + kf)*64 + lane)*8;
      bf16x8 Bdh = *(const bf16x8*)(wdnh + dOff);
      bf16x8 Bdl = *(const bf16x8*)(wdnl + dOff);
      #pragma unroll
      for (int mt = 0; mt < 4; mt++) {
        oc[p][mt] = MFMA(Ah[mt], Bdh, oc[p][mt]);
        oc[p][mt] = MFMA(Ah[mt], Bdl, oc[p][mt]);
        oc[p][mt] = MFMA(Al[mt], Bdh, oc[p][mt]);
      }
    }
  }
  #pragma unroll
  for (int p = 0; p < 2; p++)
    #pragma unroll
    for (int mt = 0; mt < 4; mt++)
      #pragma unroll
      for (int r = 0; r < 4; r++) {
        int m = mt*16 + hi*4 + r, e = (2*wv+p)*16 + l15;
        float* hp = h + (tok0 + m)*Ec + e;
        *hp += oc[p][mt][r];
      }
}

// ---------------- output head ----------------
__global__ __launch_bounds__(256) void k_out(const float* __restrict__ h,
    const float* __restrict__ postw, const float* __restrict__ wout,
    const float* __restrict__ bout, float* __restrict__ out, int B) {
  int gw = (blockIdx.x * blockDim.x + threadIdx.x) >> 6;
  int lane = threadIdx.x & 63;
  if (gw >= B) return;
  const float* row = h + ((size_t)gw*Sc + (Sc-1))*Ec;
  float v0 = row[lane], v1 = row[64+lane];
  float sum = v0+v1, sq = v0*v0+v1*v1;
  #pragma unroll
  for (int m = 1; m < 64; m <<= 1) { sum += __shfl_xor(sum, m); sq += __shfl_xor(sq, m); }
  float mu = sum * (1.f/128.f);
  float rs = rsqrtf(sq*(1.f/128.f) - mu*mu + EPSc);
  float d = (v0-mu)*rs*postw[lane]*wout[lane] + (v1-mu)*rs*postw[64+lane]*wout[64+lane];
  #pragma unroll
  for (int m = 1; m < 64; m <<= 1) d += __shfl_xor(d, m);
  if (lane == 0) out[gw] = d + bout[0];
}

extern "C" void kernel_launch(void* const* d_in, const int* in_sizes, int n_in,
                              void* d_out, int out_size, void* d_ws, size_t ws_size,
                              hipStream_t stream) {
  const float* x     = (const float*)d_in[0];
  const float* w_in  = (const float*)d_in[1];
  const float* b_in  = (const float*)d_in[2];
  const float* ln1_w = (const float*)d_in[3];
  const float* wg    = (const float*)d_in[4];
  const float* rk    = (const float*)d_in[5];
  const float* bcell = (const float*)d_in[6];
  const float* gn_w  = (const float*)d_in[7];
  const float* ln2_w = (const float*)d_in[8];
  const float* wup   = (const float*)d_in[9];
  const float* wdn   = (const float*)d_in[10];
  const float* postw = (const float*)d_in[11];
  const float* w_out = (const float*)d_in[12];
  const float* b_out = (const float*)d_in[13];
  float* out = (float*)d_out;

  char* p = (char*)d_ws;
  float* h    = (float*)p;            p += 134217728;   // [4096][64][128] fp32
  short* wch  = (short*)p;            p += 131072;
  short* wcl  = (short*)p;            p += 131072;
  short* wuph = (short*)p;            p += 131072;
  short* wupl = (short*)p;            p += 131072;
  short* wdnh = (short*)p;            p += 65536;
  short* wdnl = (short*)p;            p += 65536;

  k_prep_w<<<64, 256, 0, stream>>>(wg, rk, wup, wdn, wch, wcl,
                                   wuph, wupl, wdnh, wdnl);
  for (int ib = 0; ib < 2; ib++) {
    k_scan7<<<Bc/16, 512, 0, stream>>>(h, x, w_in, b_in,
                                       wch + ib*32768, wcl + ib*32768,
                                       bcell + ib*512, ln1_w + ib*128, gn_w + ib*128,
                                       ib == 0 ? 1 : 0);
    k_ffn6<<<(Bc*Sc)/64, 256, 0, stream>>>(h, ln2_w + ib*128,
                                           wuph + ib*32768, wupl + ib*32768,
                                           wdnh + ib*16384, wdnl + ib*16384);
  }
  k_out<<<Bc/4, 256, 0, stream>>>(h, postw, w_out, b_out, out, Bc);
}

// Round 14
// 507.540 us; speedup vs baseline: 7.4113x; 1.0210x over previous
//
#include <hip/hip_runtime.h>
#include <math.h>

#define Bc 4096
#define NHc 4
#define HDc 32
#define Ec 128
#define Sc 64
#define EPSc 1e-5f

using bf16x8 = __attribute__((ext_vector_type(8))) short;
using f32x4  = __attribute__((ext_vector_type(4))) float;

#define MFMA(a,b,c) __builtin_amdgcn_mfma_f32_16x16x32_bf16((a),(b),(c),0,0,0)
#define RCP(x) __builtin_amdgcn_rcpf(x)

__device__ __forceinline__ short f2bf(float f) {
  union { float f; unsigned u; } v; v.f = f;
  unsigned r = v.u + 0x7fffu + ((v.u >> 16) & 1u);
  return (short)(r >> 16);
}
__device__ __forceinline__ float bf2f(short s) {
  union { unsigned u; float f; } v; v.u = ((unsigned)(unsigned short)s) << 16;
  return v.f;
}
__device__ __forceinline__ float asf(unsigned u) {
  union { unsigned u; float f; } v; v.u = u; return v.f;
}
__device__ __forceinline__ unsigned asu(float f) {
  union { float f; unsigned u; } v; v.f = f; return v.u;
}
__device__ __forceinline__ unsigned pack2(short lo, short hi) {
  return (unsigned)(unsigned short)lo | ((unsigned)(unsigned short)hi << 16);
}
// truncation-hi split: hi = top 16 bits, lo = RNE(v - hi). Pair error ~2^-18|v|.
__device__ __forceinline__ void splitT(float v, short& h16, short& l16) {
  unsigned u = asu(v);
  h16 = (short)(u >> 16);
  l16 = f2bf(v - asf(u & 0xffff0000u));
}

// exact-grade GELU via A&S 7.1.26 erf poly (|err| <= 1.5e-7)
__device__ __forceinline__ float gelu_exact(float g) {
  float x  = g * 0.70710678118654752f;
  float ax = fabsf(x);
  float t  = RCP(1.f + 0.3275911f*ax);
  float y  = t*(0.254829592f + t*(-0.284496736f + t*(1.421413741f
           + t*(-1.453152027f + t*1.061405429f))));
  float e  = __expf(-ax*ax);
  float er = 1.f - y*e;
  er = (x < 0.f) ? -er : er;
  return 0.5f*g*(1.f + er);
}

// ---------------- weight prep: fp32 -> hi/lo bf16 fragment order (64 blocks) ----------------
__global__ void k_prep_w(const float* __restrict__ wg, const float* __restrict__ rk,
    const float* __restrict__ wup, const float* __restrict__ wdn,
    short* __restrict__ wch, short* __restrict__ wcl,
    short* __restrict__ wuph, short* __restrict__ wupl,
    short* __restrict__ wdnh, short* __restrict__ wdnl) {
  int ib = blockIdx.x >> 5;
  int ck = blockIdx.x & 31;
  int tid = threadIdx.x;
  const float* wgp = wg + ib*16384;   // [4][NH][HD(o)][HD(d)]
  const float* rkp = rk + ib*16384;   // [NH][HD(d)][4][HD(o)]
  for (int idx = ck*1024 + tid; idx < ck*1024 + 1024; idx += 256) {
    int j = idx & 7, lane = (idx>>3)&63, kf = (idx>>9)&1, nt = (idx>>10)&7, hh = idx>>13;
    int n = nt*16 + (lane&15); int g = n>>5, o = n&31;
    int k = kf*32 + (lane>>4)*8 + j;
    float v = (k < 32) ? wgp[((g*NHc+hh)*HDc + o)*HDc + k]
                       : rkp[((hh*HDc + (k-32))*4 + g)*HDc + o];
    short hi16 = f2bf(v);
    wch[ib*32768 + idx] = hi16;
    wcl[ib*32768 + idx] = f2bf(v - bf2f(hi16));
  }
  const float* wupp = wup + ib*32768;  // [128][256]
  for (int idx = ck*1024 + tid; idx < ck*1024 + 1024; idx += 256) {
    int j = idx&7, lane=(idx>>3)&63, kf=(idx>>9)&3, nt = idx>>11;
    int n = nt*16 + (lane&15); int k = kf*32 + (lane>>4)*8 + j;
    float v = wupp[k*256 + n];
    short hi16 = f2bf(v);
    wuph[ib*32768 + idx] = hi16;
    wupl[ib*32768 + idx] = f2bf(v - bf2f(hi16));
  }
  const float* wdnp = wdn + ib*16384;  // [128][128]
  for (int idx = ck*512 + tid; idx < ck*512 + 512; idx += 256) {
    int j = idx&7, lane=(idx>>3)&63, kf=(idx>>9)&3, nt = idx>>11;
    int n = nt*16+(lane&15); int k = kf*32+(lane>>4)*8+j;
    float v = wdnp[k*128 + n];
    short hi16 = f2bf(v);
    wdnh[ib*16384 + idx] = hi16;
    wdnl[ib*16384 + idx] = f2bf(v - bf2f(hi16));
  }
}

// ---------------- fused scan, 8-wave, 4-term split (fp32-exact gates) ----------------
// WG = 16 batches, 8 waves = (head hh, q-half p). 1 WG/CU, 2 waves/SIMD.
// s-loop unrolled x2 so the s&1 double-buffer selectors are compile-time.
__global__ __launch_bounds__(512, 2) void k_scan7(float* __restrict__ h,
    const float* __restrict__ x, const float* __restrict__ w_in,
    const float* __restrict__ b_in,
    const short* __restrict__ wch, const short* __restrict__ wcl,
    const float* __restrict__ bcell, const float* __restrict__ ln1w,
    const float* __restrict__ gnw, int first) {
  __shared__ short ybh[2][4][16][40];
  __shared__ short ybl[2][4][16][40];
  __shared__ float LNp[2][4][16][2];
  const int tid = threadIdx.x;
  const int wid = tid >> 6;
  const int hh = wid >> 1;
  const int p  = wid & 1;
  const int lane = tid & 63;
  const int l15 = lane & 15, hi = lane >> 4;
  const int bg = blockIdx.x;

  bf16x8 Bh[4][2], Bl[4][2];
  #pragma unroll
  for (int i = 0; i < 4; i++)
    #pragma unroll
    for (int kf = 0; kf < 2; kf++) {
      int off = ((hh*16 + (2*i+p)*2 + kf)*64 + lane)*8;
      Bh[i][kf] = *(const bf16x8*)(wch + off);
      Bl[i][kf] = *(const bf16x8*)(wcl + off);
    }

  float biasv[4];
  #pragma unroll
  for (int i = 0; i < 4; i++)
    biasv[i] = bcell[(i*NHc + hh)*HDc + p*16 + l15];
  float lnw[8], gwv[8];
  #pragma unroll
  for (int j = 0; j < 8; j++) {
    lnw[j] = ln1w[hh*32 + hi*8 + j];
    gwv[j] = gnw[hh*32 + hi*8 + j];
  }
  float wv0[8], wv1[8], wv2[8], bi[8];
  if (first) {
    #pragma unroll
    for (int j = 0; j < 8; j++) {
      int col = hh*32 + hi*8 + j;
      wv0[j] = w_in[col]; wv1[j] = w_in[128+col]; wv2[j] = w_in[256+col];
      bi[j] = b_in[col];
    }
  }

  for (int i = tid; i < 4*16*40; i += 512) {
    ybh[1][0][0][i] = 0; ybl[1][0][0][i] = 0;
  }

  float cs[4], ns[4], ms[4];
  #pragma unroll
  for (int r = 0; r < 4; r++) { cs[r]=0.f; ns[r]=0.f; ms[r]=0.f; }

  float* hbase = h + ((size_t)(bg*16 + l15)*Sc)*Ec + hh*32 + hi*8;
  const float* xbase = x + ((size_t)(bg*16 + l15)*Sc)*3;
  float4 ha, hb;
  float xa0, xa1, xa2;
  if (first) {
    xa0 = xbase[0]; xa1 = xbase[1]; xa2 = xbase[2];
  } else {
    ha = *(const float4*)(hbase);
    hb = *(const float4*)(hbase + 4);
  }
  float hvprev[8];

  __syncthreads();

  #pragma unroll 2
  for (int s = 0; s < Sc; s++) {
    float hv[8];
    if (first) {
      #pragma unroll
      for (int j = 0; j < 8; j++)
        hv[j] = bi[j] + xa0*wv0[j] + xa1*wv1[j] + xa2*wv2[j];
      if (s < 63) {
        xa0 = xbase[(s+1)*3]; xa1 = xbase[(s+1)*3+1]; xa2 = xbase[(s+1)*3+2];
      }
    } else {
      *(float4*)&hv[0] = ha; *(float4*)&hv[4] = hb;
      if (s < 63) {
        ha = *(const float4*)(hbase + (s+1)*Ec);
        hb = *(const float4*)(hbase + (s+1)*Ec + 4);
      }
    }
    // ---- LN1 partials ----
    float sum = 0.f, sq = 0.f;
    #pragma unroll
    for (int j = 0; j < 8; j++) { sum += hv[j]; sq += hv[j]*hv[j]; }
    sum += __shfl_xor(sum, 16); sq += __shfl_xor(sq, 16);
    sum += __shfl_xor(sum, 32); sq += __shfl_xor(sq, 32);
    if (p == 0 && hi == 0) { LNp[s&1][hh][l15][0] = sum; LNp[s&1][hh][l15][1] = sq; }
    __syncthreads();
    // packed float2 reads; same add order as scalar version (bit-identical)
    float2 q0 = *(const float2*)&LNp[s&1][0][l15][0];
    float2 q1 = *(const float2*)&LNp[s&1][1][l15][0];
    float2 q2 = *(const float2*)&LNp[s&1][2][l15][0];
    float2 q3 = *(const float2*)&LNp[s&1][3][l15][0];
    float tsum = q0.x + q1.x + q2.x + q3.x;
    float tsq  = q0.y + q1.y + q2.y + q3.y;
    float mu = tsum * (1.f/128.f);
    float rs = rsqrtf(tsq*(1.f/128.f) - mu*mu + EPSc);

    // ---- hn A-frag hi/lo (RNE split, explicit pair packing — bit-identical) ----
    bf16x8 Ah, Al;
    {
      unsigned hw[4], lw[4];
      #pragma unroll
      for (int jp = 0; jp < 4; jp++) {
        float hn0 = (hv[2*jp]-mu)*rs*lnw[2*jp];
        float hn1 = (hv[2*jp+1]-mu)*rs*lnw[2*jp+1];
        short h0 = f2bf(hn0), h1 = f2bf(hn1);
        short l0 = f2bf(hn0 - bf2f(h0)), l1 = f2bf(hn1 - bf2f(h1));
        hw[jp] = pack2(h0, h1);
        lw[jp] = pack2(l0, l1);
      }
      __builtin_memcpy(&Ah, hw, 16);
      __builtin_memcpy(&Al, lw, 16);
    }
    const int sbY = (s&1)^1;
    bf16x8 Yh = *(const bf16x8*)&ybh[sbY][hh][l15][hi*8];
    bf16x8 Yl = *(const bf16x8*)&ybl[sbY][hh][l15][hi*8];

    // ---- deferred mh_ln + residual for step s-1 (parity-alternating wave) ----
    if (s && ((s & 1) == p)) {
      float y8[8], s2 = 0.f, q2r = 0.f;
      #pragma unroll
      for (int j = 0; j < 8; j++) {
        y8[j] = bf2f(Yh[j]) + bf2f(Yl[j]);
        s2 += y8[j]; q2r += y8[j]*y8[j];
      }
      s2 += __shfl_xor(s2, 16); q2r += __shfl_xor(q2r, 16);
      s2 += __shfl_xor(s2, 32); q2r += __shfl_xor(q2r, 32);
      float mu2 = s2 * (1.f/32.f);
      float rs2 = rsqrtf(q2r*(1.f/32.f) - mu2*mu2 + EPSc);
      float4 o0, o1;
      o0.x = hvprev[0] + (y8[0]-mu2)*rs2*gwv[0];
      o0.y = hvprev[1] + (y8[1]-mu2)*rs2*gwv[1];
      o0.z = hvprev[2] + (y8[2]-mu2)*rs2*gwv[2];
      o0.w = hvprev[3] + (y8[3]-mu2)*rs2*gwv[3];
      o1.x = hvprev[4] + (y8[4]-mu2)*rs2*gwv[4];
      o1.y = hvprev[5] + (y8[5]-mu2)*rs2*gwv[5];
      o1.z = hvprev[6] + (y8[6]-mu2)*rs2*gwv[6];
      o1.w = hvprev[7] + (y8[7]-mu2)*rs2*gwv[7];
      *(float4*)(hbase + (size_t)(s-1)*Ec)     = o0;
      *(float4*)(hbase + (size_t)(s-1)*Ec + 4) = o1;
    }
    #pragma unroll
    for (int j = 0; j < 8; j++) hvprev[j] = hv[j];

    // ---- gates MFMA: 4 ntiles x 8 split terms ----
    f32x4 acc[4];
    #pragma unroll
    for (int i = 0; i < 4; i++) {
      f32x4 c; c[0]=biasv[i]; c[1]=biasv[i]; c[2]=biasv[i]; c[3]=biasv[i];
      c = MFMA(Ah, Bh[i][0], c);
      c = MFMA(Ah, Bl[i][0], c);
      c = MFMA(Al, Bh[i][0], c);
      c = MFMA(Al, Bl[i][0], c);
      c = MFMA(Yh, Bh[i][1], c);
      c = MFMA(Yh, Bl[i][1], c);
      c = MFMA(Yl, Bh[i][1], c);
      acc[i] = MFMA(Yl, Bl[i][1], c);
    }

    // ---- cell update (single-exp ig/fg) ----
    #pragma unroll
    for (int r = 0; r < 4; r++) {
      float iraw = acc[0][r];
      float fraw = acc[1][r];
      float zraw = acc[2][r];
      float oraw = acc[3][r];
      float ax  = fabsf(fraw);
      float lsg = fminf(fraw, 0.f) - __logf(1.f + __expf(-ax));
      float lfm = ms[r] + lsg;
      float diff = iraw - lfm;
      float emin = __expf(-fabsf(diff));
      bool cnd = (ns[r] == 0.f) | (diff >= 0.f);
      float mnew = cnd ? iraw : lfm;
      float ig = cnd ? 1.f : emin;
      float fg = cnd ? emin : 1.f;
      float og = RCP(1.f + __expf(-oraw));
      float e2 = __expf(2.f*zraw);
      float th = 1.f - 2.f*RCP(e2 + 1.f);
      float cn = fg*cs[r] + ig*th;
      float nn = fg*ns[r] + ig;
      cs[r] = cn; ns[r] = nn; ms[r] = mnew;
      float y = og*cn*RCP(nn);
      short y16 = f2bf(y);
      ybh[s&1][hh][hi*4+r][p*16+l15] = y16;
      ybl[s&1][hh][hi*4+r][p*16+l15] = f2bf(y - bf2f(y16));
    }
  }

  // ---- epilogue: mh_ln + residual for s=63 ----
  __syncthreads();
  if (p == 0) {
    bf16x8 Yh = *(const bf16x8*)&ybh[(Sc-1)&1][hh][l15][hi*8];
    bf16x8 Yl = *(const bf16x8*)&ybl[(Sc-1)&1][hh][l15][hi*8];
    float y8[8], s2 = 0.f, q2r = 0.f;
    #pragma unroll
    for (int j = 0; j < 8; j++) {
      y8[j] = bf2f(Yh[j]) + bf2f(Yl[j]);
      s2 += y8[j]; q2r += y8[j]*y8[j];
    }
    s2 += __shfl_xor(s2, 16); q2r += __shfl_xor(q2r, 16);
    s2 += __shfl_xor(s2, 32); q2r += __shfl_xor(q2r, 32);
    float mu2 = s2 * (1.f/32.f);
    float rs2 = rsqrtf(q2r*(1.f/32.f) - mu2*mu2 + EPSc);
    float4 o0, o1;
    o0.x = hvprev[0] + (y8[0]-mu2)*rs2*gwv[0];
    o0.y = hvprev[1] + (y8[1]-mu2)*rs2*gwv[1];
    o0.z = hvprev[2] + (y8[2]-mu2)*rs2*gwv[2];
    o0.w = hvprev[3] + (y8[3]-mu2)*rs2*gwv[3];
    o1.x = hvprev[4] + (y8[4]-mu2)*rs2*gwv[4];
    o1.y = hvprev[5] + (y8[5]-mu2)*rs2*gwv[5];
    o1.z = hvprev[6] + (y8[6]-mu2)*rs2*gwv[6];
    o1.w = hvprev[7] + (y8[7]-mu2)*rs2*gwv[7];
    *(float4*)(hbase + (size_t)(Sc-1)*Ec)     = o0;
    *(float4*)(hbase + (size_t)(Sc-1)*Ec + 4) = o1;
  }
}

// ---------------- fused FFN (fp32-grade, trunc-hi splits) ----------------
__global__ __launch_bounds__(256) void k_ffn6(float* __restrict__ h,
    const float* __restrict__ ln2w,
    const short* __restrict__ wuph, const short* __restrict__ wupl,
    const short* __restrict__ wdnh, const short* __restrict__ wdnl) {
  __shared__ short bufH[8192];   // [64 tok][128] hi, XOR-swizzled ^((row&7)<<4)
  __shared__ short bufL[8192];
  size_t tok0 = (size_t)blockIdx.x * 64;
  int tid = threadIdx.x;
  int wv = tid >> 6, lane = tid & 63, l15 = lane & 15, hi = lane >> 4;

  { // LN2 -> bufH/bufL (explicit pair packing — bit-identical values)
    int t = tid >> 2, sub = tid & 3;
    const float* row = h + (tok0 + t)*Ec + sub*32;
    float v[32];
    #pragma unroll
    for (int q = 0; q < 8; q++) *(float4*)&v[q*4] = *(const float4*)&row[q*4];
    float sum = 0.f, sq = 0.f;
    #pragma unroll
    for (int j = 0; j < 32; j++) { sum += v[j]; sq += v[j]*v[j]; }
    sum += __shfl_xor(sum,1); sq += __shfl_xor(sq,1);
    sum += __shfl_xor(sum,2); sq += __shfl_xor(sq,2);
    float mu = sum * (1.f/128.f);
    float rs = rsqrtf(sq*(1.f/128.f) - mu*mu + EPSc);
    #pragma unroll
    for (int q2 = 0; q2 < 4; q2++) {
      unsigned hw[4], lw[4];
      #pragma unroll
      for (int jp = 0; jp < 4; jp++) {
        float hn0 = (v[q2*8+2*jp]-mu)*rs*ln2w[sub*32+q2*8+2*jp];
        float hn1 = (v[q2*8+2*jp+1]-mu)*rs*ln2w[sub*32+q2*8+2*jp+1];
        short h0, l0, h1, l1;
        splitT(hn0, h0, l0);
        splitT(hn1, h1, l1);
        hw[jp] = pack2(h0, h1);
        lw[jp] = pack2(l0, l1);
      }
      int byte = (t*256 + sub*64 + q2*16) ^ ((t&7)<<4);
      *(uint4*)((char*)bufH + byte) = *(uint4*)hw;
      *(uint4*)((char*)bufL + byte) = *(uint4*)lw;
    }
  }
  __syncthreads();

  // up GEMM
  f32x4 ag[2][4], au[2][4];
  #pragma unroll
  for (int p = 0; p < 2; p++)
    #pragma unroll
    for (int mt = 0; mt < 4; mt++)
      #pragma unroll
      for (int r = 0; r < 4; r++) { ag[p][mt][r]=0.f; au[p][mt][r]=0.f; }
  #pragma unroll 1
  for (int kf = 0; kf < 4; kf++) {
    bf16x8 Ah[4], Al[4];
    #pragma unroll
    for (int mt = 0; mt < 4; mt++) {
      int rw = mt*16 + l15;
      int byte = (rw*256 + kf*64 + hi*16) ^ ((rw&7)<<4);
      Ah[mt] = *(const bf16x8*)((const char*)bufH + byte);
      Al[mt] = *(const bf16x8*)((const char*)bufL + byte);
    }
    #pragma unroll
    for (int p = 0; p < 2; p++) {
      int gOff = (((2*wv+p)*4 + kf)*64 + lane)*8;
      int uOff = (((8+2*wv+p)*4 + kf)*64 + lane)*8;
      bf16x8 Bgh = *(const bf16x8*)(wuph + gOff);
      bf16x8 Bgl = *(const bf16x8*)(wupl + gOff);
      bf16x8 Buh = *(const bf16x8*)(wuph + uOff);
      bf16x8 Bul = *(const bf16x8*)(wupl + uOff);
      #pragma unroll
      for (int mt = 0; mt < 4; mt++) {
        ag[p][mt] = MFMA(Ah[mt], Bgh, ag[p][mt]);
        ag[p][mt] = MFMA(Ah[mt], Bgl, ag[p][mt]);
        ag[p][mt] = MFMA(Al[mt], Bgh, ag[p][mt]);
        au[p][mt] = MFMA(Ah[mt], Buh, au[p][mt]);
        au[p][mt] = MFMA(Ah[mt], Bul, au[p][mt]);
        au[p][mt] = MFMA(Al[mt], Buh, au[p][mt]);
      }
    }
  }
  __syncthreads();
  // exact GELU(gate)*up -> bufH/bufL
  #pragma unroll
  for (int p = 0; p < 2; p++)
    #pragma unroll
    for (int mt = 0; mt < 4; mt++)
      #pragma unroll
      for (int r = 0; r < 4; r++) {
        float g = ag[p][mt][r], u = au[p][mt][r];
        float a = gelu_exact(g)*u;
        int m = mt*16 + hi*4 + r, f = (2*wv+p)*16 + l15;
        int byte = (m*256 + f*2) ^ ((m&7)<<4);
        short a16, al16; splitT(a, a16, al16);
        *(short*)((char*)bufH + byte) = a16;
        *(short*)((char*)bufL + byte) = al16;
      }
  __syncthreads();

  // down GEMM + residual
  f32x4 oc[2][4];
  #pragma unroll
  for (int p = 0; p < 2; p++)
    #pragma unroll
    for (int mt = 0; mt < 4; mt++)
      #pragma unroll
      for (int r = 0; r < 4; r++) oc[p][mt][r] = 0.f;
  #pragma unroll 1
  for (int kf = 0; kf < 4; kf++) {
    bf16x8 Ah[4], Al[4];
    #pragma unroll
    for (int mt = 0; mt < 4; mt++) {
      int rw = mt*16 + l15;
      int byte = (rw*256 + kf*64 + hi*16) ^ ((rw&7)<<4);
      Ah[mt] = *(const bf16x8*)((const char*)bufH + byte);
      Al[mt] = *(const bf16x8*)((const char*)bufL + byte);
    }
    #pragma unroll
    for (int p = 0; p < 2; p++) {
      int dOff = (((2*wv+p)*4 + kf)*64 + lane)*8;
      bf16x8 Bdh = *(const bf16x8*)(wdnh + dOff);
      bf16x8 Bdl = *(const bf16x8*)(wdnl + dOff);
      #pragma unroll
      for (int mt = 0; mt < 4; mt++) {
        oc[p][mt] = MFMA(Ah[mt], Bdh, oc[p][mt]);
        oc[p][mt] = MFMA(Ah[mt], Bdl, oc[p][mt]);
        oc[p][mt] = MFMA(Al[mt], Bdh, oc[p][mt]);
      }
    }
  }
  #pragma unroll
  for (int p = 0; p < 2; p++)
    #pragma unroll
    for (int mt = 0; mt < 4; mt++)
      #pragma unroll
      for (int r = 0; r < 4; r++) {
        int m = mt*16 + hi*4 + r, e = (2*wv+p)*16 + l15;
        float* hp = h + (tok0 + m)*Ec + e;
        *hp += oc[p][mt][r];
      }
}

// ---------------- output head ----------------
__global__ __launch_bounds__(256) void k_out(const float* __restrict__ h,
    const float* __restrict__ postw, const float* __restrict__ wout,
    const float* __restrict__ bout, float* __restrict__ out, int B) {
  int gw = (blockIdx.x * blockDim.x + threadIdx.x) >> 6;
  int lane = threadIdx.x & 63;
  if (gw >= B) return;
  const float* row = h + ((size_t)gw*Sc + (Sc-1))*Ec;
  float v0 = row[lane], v1 = row[64+lane];
  float sum = v0+v1, sq = v0*v0+v1*v1;
  #pragma unroll
  for (int m = 1; m < 64; m <<= 1) { sum += __shfl_xor(sum, m); sq += __shfl_xor(sq, m); }
  float mu = sum * (1.f/128.f);
  float rs = rsqrtf(sq*(1.f/128.f) - mu*mu + EPSc);
  float d = (v0-mu)*rs*postw[lane]*wout[lane] + (v1-mu)*rs*postw[64+lane]*wout[64+lane];
  #pragma unroll
  for (int m = 1; m < 64; m <<= 1) d += __shfl_xor(d, m);
  if (lane == 0) out[gw] = d + bout[0];
}

extern "C" void kernel_launch(void* const* d_in, const int* in_sizes, int n_in,
                              void* d_out, int out_size, void* d_ws, size_t ws_size,
                              hipStream_t stream) {
  const float* x     = (const float*)d_in[0];
  const float* w_in  = (const float*)d_in[1];
  const float* b_in  = (const float*)d_in[2];
  const float* ln1_w = (const float*)d_in[3];
  const float* wg    = (const float*)d_in[4];
  const float* rk    = (const float*)d_in[5];
  const float* bcell = (const float*)d_in[6];
  const float* gn_w  = (const float*)d_in[7];
  const float* ln2_w = (const float*)d_in[8];
  const float* wup   = (const float*)d_in[9];
  const float* wdn   = (const float*)d_in[10];
  const float* postw = (const float*)d_in[11];
  const float* w_out = (const float*)d_in[12];
  const float* b_out = (const float*)d_in[13];
  float* out = (float*)d_out;

  char* p = (char*)d_ws;
  float* h    = (float*)p;            p += 134217728;   // [4096][64][128] fp32
  short* wch  = (short*)p;            p += 131072;
  short* wcl  = (short*)p;            p += 131072;
  short* wuph = (short*)p;            p += 131072;
  short* wupl = (short*)p;            p += 131072;
  short* wdnh = (short*)p;            p += 65536;
  short* wdnl = (short*)p;            p += 65536;

  k_prep_w<<<64, 256, 0, stream>>>(wg, rk, wup, wdn, wch, wcl,
                                   wuph, wupl, wdnh, wdnl);
  for (int ib = 0; ib < 2; ib++) {
    k_scan7<<<Bc/16, 512, 0, stream>>>(h, x, w_in, b_in,
                                       wch + ib*32768, wcl + ib*32768,
                                       bcell + ib*512, ln1_w + ib*128, gn_w + ib*128,
                                       ib == 0 ? 1 : 0);
    k_ffn6<<<(Bc*Sc)/64, 256, 0, stream>>>(h, ln2_w + ib*128,
                                           wuph + ib*32768, wupl + ib*32768,
                                           wdnh + ib*16384, wdnl + ib*16384);
  }
  k_out<<<Bc/4, 256, 0, stream>>>(h, postw, w_out, b_out, out, Bc);
}